// Round 1
// baseline (6948.747 us; speedup 1.0000x reference)
//
#include <hip/hip_runtime.h>
#include <hip/hip_bf16.h>

#define N_NODES  50000
#define N_EDGES  800000
#define N_GRAPHS 64
#define EMB      24
#define MDIM     64
#define EDGE_IN  57
#define EH       114   // EDGE_IN*2
#define CH       256   // M_DIM*4
#define NIN      88    // EMB+MDIM
#define NH       48    // EMB*2
#define FIN      72
#define MLP      256
#define NPB      16
#define CHUNK    12800

__device__ __forceinline__ float siluf(float x) {
    // x * sigmoid(x); rcp approx (~1e-7 rel) + hw exp
    return x * __builtin_amdgcn_rcpf(1.0f + __expf(-x));
}

// ---------------- embedding: feats0 = emb_table[z] @ emb_w + emb_b ----------
__global__ void embed_kernel(const int* __restrict__ z, const float* __restrict__ table,
                             const float* __restrict__ w, const float* __restrict__ b,
                             const int* __restrict__ batch, float* __restrict__ f0,
                             float* __restrict__ cnt)
{
    int n = blockIdx.x * blockDim.x + threadIdx.x;
    if (n >= N_NODES) return;
    float r[EMB];
    const float4* tr = reinterpret_cast<const float4*>(table + z[n] * EMB);
    #pragma unroll
    for (int q = 0; q < 6; q++) {
        float4 v = tr[q];
        r[q*4] = v.x; r[q*4+1] = v.y; r[q*4+2] = v.z; r[q*4+3] = v.w;
    }
    float o[EMB];
    #pragma unroll
    for (int j = 0; j < EMB; j++) o[j] = b[j];
    #pragma unroll
    for (int i = 0; i < EMB; i++) {
        #pragma unroll
        for (int j = 0; j < EMB; j++) o[j] = fmaf(r[i], w[i*EMB + j], o[j]);
    }
    float4* dst = reinterpret_cast<float4*>(f0 + (size_t)n * EMB);
    #pragma unroll
    for (int q = 0; q < 6; q++) dst[q] = make_float4(o[q*4], o[q*4+1], o[q*4+2], o[q*4+3]);
    atomicAdd(&cnt[batch[n]], 1.0f);
}

// ---------------- edge kernel: fused edge MLP + coor MLP + atomics ----------
template<int UPDATE_COOR>
__global__ __launch_bounds__(512, 2)
void edge_kernel(const float* __restrict__ feats, const float* __restrict__ coors,
                 const int* __restrict__ esrc, const int* __restrict__ edst,
                 const float* __restrict__ ew1, const float* __restrict__ eb1,
                 const float* __restrict__ ew2, const float* __restrict__ eb2,
                 const float* __restrict__ cw1, const float* __restrict__ cb1,
                 const float* __restrict__ cw2, const float* __restrict__ cb2,
                 float* __restrict__ m_i, float* __restrict__ cdelta)
{
    __shared__ float s_ew1t[EH * EDGE_IN]; // [k][i]
    __shared__ float s_eb1[EH];
    __shared__ float s_ew2[EH * MDIM];     // [k][j]
    __shared__ float s_eb2[MDIM];
    __shared__ float s_cw1t[CH * MDIM];    // [k][j]
    __shared__ float s_cb1[CH];
    __shared__ float s_cw2[CH];

    const int tid = threadIdx.x;
    for (int idx = tid; idx < EH * EDGE_IN; idx += 512) {
        int k = idx / EDGE_IN, i = idx - k * EDGE_IN;
        s_ew1t[idx] = ew1[i * EH + k];
    }
    for (int idx = tid; idx < EH * MDIM; idx += 512) s_ew2[idx] = ew2[idx];
    for (int idx = tid; idx < CH * MDIM; idx += 512) {
        int k = idx >> 6, j = idx & 63;
        s_cw1t[idx] = cw1[j * CH + k];
    }
    if (tid < EH)  s_eb1[tid] = eb1[tid];
    if (tid < MDIM) s_eb2[tid] = eb2[tid];
    if (tid < CH)  s_cb1[tid] = cb1[tid];
    if (tid >= 256) s_cw2[tid - 256] = cw2[tid - 256];
    __syncthreads();

    int e = blockIdx.x * 512 + tid;
    if (e >= N_EDGES) return;

    int s = esrc[e], d = edst[e];
    float rx = coors[s*3+0] - coors[d*3+0];
    float ry = coors[s*3+1] - coors[d*3+1];
    float rz = coors[s*3+2] - coors[d*3+2];
    float d2 = rx*rx + ry*ry + rz*rz;

    float e_in[EDGE_IN];
    const float4* fd = reinterpret_cast<const float4*>(feats + (size_t)d * EMB);
    const float4* fs = reinterpret_cast<const float4*>(feats + (size_t)s * EMB);
    #pragma unroll
    for (int q = 0; q < 6; q++) {
        float4 v = fd[q];
        e_in[q*4] = v.x; e_in[q*4+1] = v.y; e_in[q*4+2] = v.z; e_in[q*4+3] = v.w;
    }
    #pragma unroll
    for (int q = 0; q < 6; q++) {
        float4 v = fs[q];
        e_in[24+q*4] = v.x; e_in[24+q*4+1] = v.y; e_in[24+q*4+2] = v.z; e_in[24+q*4+3] = v.w;
    }
    {
        float dsv0 = d2, dsv1 = d2 * 0.5f, dsv2 = d2 * 0.25f, dsv3 = d2 * 0.125f;
        e_in[48] = sinf(dsv0); e_in[49] = sinf(dsv1); e_in[50] = sinf(dsv2); e_in[51] = sinf(dsv3);
        e_in[52] = cosf(dsv0); e_in[53] = cosf(dsv1); e_in[54] = cosf(dsv2); e_in[55] = cosf(dsv3);
        e_in[56] = d2;
    }

    // phase A: m_ij = silu(silu(e_in@ew1+eb1)@ew2 + eb2)
    float m[MDIM];
    #pragma unroll
    for (int j = 0; j < MDIM; j++) m[j] = s_eb2[j];
    for (int k = 0; k < EH; k++) {
        const float* w1 = &s_ew1t[k * EDGE_IN];
        float a0 = 0.f, a1 = 0.f, a2 = 0.f, a3 = 0.f;
        #pragma unroll
        for (int i = 0; i < 56; i += 4) {
            a0 = fmaf(e_in[i],   w1[i],   a0);
            a1 = fmaf(e_in[i+1], w1[i+1], a1);
            a2 = fmaf(e_in[i+2], w1[i+2], a2);
            a3 = fmaf(e_in[i+3], w1[i+3], a3);
        }
        a0 = fmaf(e_in[56], w1[56], a0);
        float h = siluf(s_eb1[k] + ((a0 + a1) + (a2 + a3)));
        const float* w2 = &s_ew2[k * MDIM];
        #pragma unroll
        for (int j = 0; j < MDIM; j++) m[j] = fmaf(h, w2[j], m[j]);
    }
    #pragma unroll
    for (int j = 0; j < MDIM; j++) m[j] = siluf(m[j]);

    // phase B: coor_w = silu(m@cw1+cb1)@cw2 + cb2
    float cacc = cb2[0];
    for (int k = 0; k < CH; k++) {
        const float* w = &s_cw1t[k * MDIM];
        float a0 = 0.f, a1 = 0.f, a2 = 0.f, a3 = 0.f;
        #pragma unroll
        for (int j = 0; j < MDIM; j += 4) {
            a0 = fmaf(m[j],   w[j],   a0);
            a1 = fmaf(m[j+1], w[j+1], a1);
            a2 = fmaf(m[j+2], w[j+2], a2);
            a3 = fmaf(m[j+3], w[j+3], a3);
        }
        float h = siluf(s_cb1[k] + ((a0 + a1) + (a2 + a3)));
        cacc = fmaf(h, s_cw2[k], cacc);
    }

    if (UPDATE_COOR) {
        atomicAdd(&cdelta[d*3+0], cacc * rx);
        atomicAdd(&cdelta[d*3+1], cacc * ry);
        atomicAdd(&cdelta[d*3+2], cacc * rz);
    }
    float* mrow = m_i + (size_t)d * MDIM;
    #pragma unroll
    for (int j = 0; j < MDIM; j++) atomicAdd(&mrow[j], m[j]);
}

// ---------------- node kernel: feats_out = feats + MLP([feats, m_i]) --------
__global__ __launch_bounds__(256)
void node_kernel(const float* __restrict__ feats, const float* __restrict__ m_i,
                 const float* __restrict__ nw1, const float* __restrict__ nb1,
                 const float* __restrict__ nw2, const float* __restrict__ nb2,
                 float* __restrict__ fout)
{
    __shared__ float s_w1t[NH * NIN]; // [k][i]
    __shared__ float s_b1[NH];
    __shared__ float s_w2[NH * EMB];  // [k][j]
    __shared__ float s_b2[EMB];
    const int tid = threadIdx.x;
    for (int idx = tid; idx < NH * NIN; idx += 256) {
        int k = idx / NIN, i = idx - k * NIN;
        s_w1t[idx] = nw1[i * NH + k];
    }
    for (int idx = tid; idx < NH * EMB; idx += 256) s_w2[idx] = nw2[idx];
    if (tid < NH) s_b1[tid] = nb1[tid];
    if (tid < EMB) s_b2[tid] = nb2[tid];
    __syncthreads();

    int n = blockIdx.x * 256 + tid;
    if (n >= N_NODES) return;

    float in[NIN];
    const float4* fp = reinterpret_cast<const float4*>(feats + (size_t)n * EMB);
    #pragma unroll
    for (int q = 0; q < 6; q++) {
        float4 v = fp[q];
        in[q*4] = v.x; in[q*4+1] = v.y; in[q*4+2] = v.z; in[q*4+3] = v.w;
    }
    const float4* mp = reinterpret_cast<const float4*>(m_i + (size_t)n * MDIM);
    #pragma unroll
    for (int q = 0; q < 16; q++) {
        float4 v = mp[q];
        in[EMB+q*4] = v.x; in[EMB+q*4+1] = v.y; in[EMB+q*4+2] = v.z; in[EMB+q*4+3] = v.w;
    }
    float o[EMB];
    #pragma unroll
    for (int j = 0; j < EMB; j++) o[j] = in[j] + s_b2[j];
    for (int k = 0; k < NH; k++) {
        const float* w1 = &s_w1t[k * NIN];
        float a0 = 0.f, a1 = 0.f, a2 = 0.f, a3 = 0.f;
        #pragma unroll
        for (int i = 0; i < NIN; i += 4) {
            a0 = fmaf(in[i],   w1[i],   a0);
            a1 = fmaf(in[i+1], w1[i+1], a1);
            a2 = fmaf(in[i+2], w1[i+2], a2);
            a3 = fmaf(in[i+3], w1[i+3], a3);
        }
        float h = siluf(s_b1[k] + ((a0 + a1) + (a2 + a3)));
        const float* w2 = &s_w2[k * EMB];
        #pragma unroll
        for (int j = 0; j < EMB; j++) o[j] = fmaf(h, w2[j], o[j]);
    }
    float4* dst = reinterpret_cast<float4*>(fout + (size_t)n * EMB);
    #pragma unroll
    for (int q = 0; q < 6; q++) dst[q] = make_float4(o[q*4], o[q*4+1], o[q*4+2], o[q*4+3]);
}

// ---------------- coors update ------------------------------------------------
__global__ void coor_kernel(const float* __restrict__ pos, const float* __restrict__ cdelta,
                            float* __restrict__ out)
{
    int i = blockIdx.x * blockDim.x + threadIdx.x;
    if (i < N_NODES * 3) out[i] = pos[i] + cdelta[i];
}

// ---------------- FFNN layer 0: x=silu(concat f0,f1,f2) -> silu(x@W+b) -------
__global__ __launch_bounds__(256)
void ffnn0_kernel(const float* __restrict__ f0, const float* __restrict__ f1,
                  const float* __restrict__ f2, const float* __restrict__ w,
                  const float* __restrict__ b, float* __restrict__ hout,
                  int n0, int nmax)
{
    __shared__ float s_xt[FIN * NPB]; // [i][nn]
    int lbase = blockIdx.x * NPB;
    for (int idx = threadIdx.x; idx < FIN * NPB; idx += 256) {
        int nn = idx / FIN, i = idx - nn * FIN;
        int n = n0 + lbase + nn;
        float v = 0.f;
        if (n < nmax) {
            float s;
            if (i < 24)      s = f0[(size_t)n * EMB + i];
            else if (i < 48) s = f1[(size_t)n * EMB + (i - 24)];
            else             s = f2[(size_t)n * EMB + (i - 48)];
            v = siluf(s);
        }
        s_xt[i * NPB + nn] = v;
    }
    __syncthreads();
    int j = threadIdx.x;
    float acc[NPB];
    #pragma unroll
    for (int nn = 0; nn < NPB; nn++) acc[nn] = b[j];
    for (int i = 0; i < FIN; i++) {
        float wv = w[i * MLP + j];
        const float* xr = &s_xt[i * NPB];
        #pragma unroll
        for (int nn = 0; nn < NPB; nn++) acc[nn] = fmaf(xr[nn], wv, acc[nn]);
    }
    #pragma unroll
    for (int nn = 0; nn < NPB; nn++) {
        int n = n0 + lbase + nn;
        if (n < nmax) hout[(size_t)(lbase + nn) * MLP + j] = siluf(acc[nn]);
    }
}

// ---------------- FFNN mid / pool layers -------------------------------------
template<int POOL>
__global__ __launch_bounds__(256)
void ffnn_mid_kernel(const float* __restrict__ hin, const float* __restrict__ w,
                     const float* __restrict__ b, float* __restrict__ hout,
                     float* __restrict__ pooled, const int* __restrict__ batch,
                     int n0, int nmax)
{
    __shared__ float s_xt[MLP * NPB]; // 16 KB, [i][nn]
    int lbase = blockIdx.x * NPB;
    for (int idx = threadIdx.x; idx < MLP * NPB; idx += 256) {
        int nn = idx >> 8, i = idx & 255;
        int n = n0 + lbase + nn;
        s_xt[i * NPB + nn] = (n < nmax) ? hin[(size_t)(lbase + nn) * MLP + i] : 0.f;
    }
    __syncthreads();
    int j = threadIdx.x;
    float acc[NPB];
    #pragma unroll
    for (int nn = 0; nn < NPB; nn++) acc[nn] = b[j];
    for (int i = 0; i < MLP; i++) {
        float wv = w[i * MLP + j];
        const float* xr = &s_xt[i * NPB];
        #pragma unroll
        for (int nn = 0; nn < NPB; nn++) acc[nn] = fmaf(xr[nn], wv, acc[nn]);
    }
    if (!POOL) {
        #pragma unroll
        for (int nn = 0; nn < NPB; nn++) {
            int n = n0 + lbase + nn;
            if (n < nmax) hout[(size_t)(lbase + nn) * MLP + j] = siluf(acc[nn]);
        }
    } else {
        float runsum = 0.f;
        int curb = -1;
        #pragma unroll
        for (int nn = 0; nn < NPB; nn++) {
            int n = n0 + lbase + nn;
            if (n < nmax) {
                int bb = batch[n];
                if (bb != curb) {
                    if (curb >= 0) atomicAdd(&pooled[curb * MLP + j], runsum);
                    runsum = 0.f; curb = bb;
                }
                runsum += siluf(acc[nn]);
            }
        }
        if (curb >= 0) atomicAdd(&pooled[curb * MLP + j], runsum);
    }
}

// ---------------- final: sigmoid((pooled/cnt) @ fow + fob) -------------------
__global__ void final_kernel(const float* __restrict__ pooled, const float* __restrict__ cnt,
                             const float* __restrict__ fow, const float* __restrict__ fob,
                             float* __restrict__ out)
{
    int t = threadIdx.x;  // 256 = 64 graphs * 4 outputs
    int bg = t >> 2, o = t & 3;
    float c = fmaxf(cnt[bg], 1.0f);
    float acc = 0.f;
    for (int i = 0; i < MLP; i++) acc = fmaf(pooled[bg * MLP + i], fow[i * 4 + o], acc);
    acc = acc / c + fob[o];
    out[t] = 1.0f / (1.0f + __expf(-acc));
}

extern "C" void kernel_launch(void* const* d_in, const int* in_sizes, int n_in,
                              void* d_out, int out_size, void* d_ws, size_t ws_size,
                              hipStream_t stream)
{
    const int*   z     = (const int*)  d_in[0];
    const float* pos   = (const float*)d_in[1];
    const int*   eidx  = (const int*)  d_in[2];
    const int*   batch = (const int*)  d_in[3];
    const float* embt  = (const float*)d_in[4];
    const float* embw  = (const float*)d_in[5];
    const float* embb  = (const float*)d_in[6];
    const float* ew1   = (const float*)d_in[7];
    const float* eb1   = (const float*)d_in[8];
    const float* ew2   = (const float*)d_in[9];
    const float* eb2   = (const float*)d_in[10];
    const float* cw1   = (const float*)d_in[11];
    const float* cb1   = (const float*)d_in[12];
    const float* cw2   = (const float*)d_in[13];
    const float* cb2   = (const float*)d_in[14];
    const float* nw1   = (const float*)d_in[15];
    const float* nb1   = (const float*)d_in[16];
    const float* nw2   = (const float*)d_in[17];
    const float* nb2   = (const float*)d_in[18];
    const float* f0w   = (const float*)d_in[19];
    const float* f0b   = (const float*)d_in[20];
    const float* f1w   = (const float*)d_in[21];
    const float* f1b   = (const float*)d_in[22];
    const float* f2w   = (const float*)d_in[23];
    const float* f2b   = (const float*)d_in[24];
    const float* fow   = (const float*)d_in[25];
    const float* fob   = (const float*)d_in[26];

    float* ws     = (float*)d_ws;
    float* f0     = ws;
    float* f1v    = f0 + (size_t)N_NODES * EMB;
    float* f2v    = f1v + (size_t)N_NODES * EMB;
    float* coorsA = f2v + (size_t)N_NODES * EMB;
    float* cdelta = coorsA + N_NODES * 3;
    float* m_i    = cdelta + N_NODES * 3;
    float* hA     = m_i + (size_t)N_NODES * MDIM;
    float* hB     = hA + (size_t)CHUNK * MLP;
    float* pooled = hB + (size_t)CHUNK * MLP;
    float* cnt    = pooled + N_GRAPHS * MLP;

    hipMemsetAsync(cdelta, 0, N_NODES * 3 * sizeof(float), stream);
    hipMemsetAsync(m_i, 0, (size_t)N_NODES * MDIM * sizeof(float), stream);
    hipMemsetAsync(pooled, 0, (N_GRAPHS * MLP + N_GRAPHS) * sizeof(float), stream);

    embed_kernel<<<(N_NODES + 255) / 256, 256, 0, stream>>>(z, embt, embw, embb, batch, f0, cnt);

    const int EBLK = (N_EDGES + 511) / 512;
    // layer 0
    edge_kernel<1><<<EBLK, 512, 0, stream>>>(f0, pos, eidx, eidx + N_EDGES,
        ew1, eb1, ew2, eb2, cw1, cb1, cw2, cb2, m_i, cdelta);
    node_kernel<<<(N_NODES + 255) / 256, 256, 0, stream>>>(f0, m_i, nw1, nb1, nw2, nb2, f1v);
    coor_kernel<<<(N_NODES * 3 + 255) / 256, 256, 0, stream>>>(pos, cdelta, coorsA);
    hipMemsetAsync(m_i, 0, (size_t)N_NODES * MDIM * sizeof(float), stream);
    // layer 1 (coors output unused downstream -> no coor atomics)
    edge_kernel<0><<<EBLK, 512, 0, stream>>>(f1v, coorsA, eidx, eidx + N_EDGES,
        ew1 + EDGE_IN * EH, eb1 + EH, ew2 + EH * MDIM, eb2 + MDIM,
        cw1 + MDIM * CH, cb1 + CH, cw2 + CH, cb2 + 1, m_i, nullptr);
    node_kernel<<<(N_NODES + 255) / 256, 256, 0, stream>>>(f1v, m_i,
        nw1 + NIN * NH, nb1 + NH, nw2 + NH * EMB, nb2 + EMB, f2v);

    // FFNN, chunked through ws ping-pong
    for (int n0 = 0; n0 < N_NODES; n0 += CHUNK) {
        int nc = (N_NODES - n0 < CHUNK) ? (N_NODES - n0) : CHUNK;
        int blocks = (nc + NPB - 1) / NPB;
        ffnn0_kernel<<<blocks, 256, 0, stream>>>(f0, f1v, f2v, f0w, f0b, hA, n0, N_NODES);
        ffnn_mid_kernel<0><<<blocks, 256, 0, stream>>>(hA, f1w, f1b, hB, nullptr, nullptr, n0, N_NODES);
        ffnn_mid_kernel<1><<<blocks, 256, 0, stream>>>(hB, f2w, f2b, nullptr, pooled, batch, n0, N_NODES);
    }

    final_kernel<<<1, 256, 0, stream>>>(pooled, cnt, fow, fob, (float*)d_out);
}

// Round 2
// 1366.592 us; speedup vs baseline: 5.0847x; 5.0847x over previous
//
#include <hip/hip_runtime.h>
#include <hip/hip_bf16.h>

#define N_NODES  50000
#define N_EDGES  800000
#define N_GRAPHS 64
#define EMB      24
#define MDIM     64
#define EDGE_IN  57
#define EH       114   // EDGE_IN*2
#define CH       256   // M_DIM*4
#define NIN      88    // EMB+MDIM
#define NH       48    // EMB*2
#define FIN      72
#define MLP      256
#define NPB      16
#define CHUNK    6400
#define ETILE    128

typedef __bf16 bf16_t;
typedef __bf16 bf16x8 __attribute__((ext_vector_type(8)));
typedef float  f32x4  __attribute__((ext_vector_type(4)));

__device__ __forceinline__ float siluf(float x) {
    return x * __builtin_amdgcn_rcpf(1.0f + __expf(-x));
}

// ---------------- embedding: feats0 = emb_table[z] @ emb_w + emb_b ----------
__global__ void embed_kernel(const int* __restrict__ z, const float* __restrict__ table,
                             const float* __restrict__ w, const float* __restrict__ b,
                             const int* __restrict__ batch, float* __restrict__ f0,
                             float* __restrict__ cnt)
{
    int n = blockIdx.x * blockDim.x + threadIdx.x;
    if (n >= N_NODES) return;
    float r[EMB];
    const float4* tr = reinterpret_cast<const float4*>(table + z[n] * EMB);
    #pragma unroll
    for (int q = 0; q < 6; q++) {
        float4 v = tr[q];
        r[q*4] = v.x; r[q*4+1] = v.y; r[q*4+2] = v.z; r[q*4+3] = v.w;
    }
    float o[EMB];
    #pragma unroll
    for (int j = 0; j < EMB; j++) o[j] = b[j];
    #pragma unroll
    for (int i = 0; i < EMB; i++) {
        #pragma unroll
        for (int j = 0; j < EMB; j++) o[j] = fmaf(r[i], w[i*EMB + j], o[j]);
    }
    float4* dst = reinterpret_cast<float4*>(f0 + (size_t)n * EMB);
    #pragma unroll
    for (int q = 0; q < 6; q++) dst[q] = make_float4(o[q*4], o[q*4+1], o[q*4+2], o[q*4+3]);
    atomicAdd(&cnt[batch[n]], 1.0f);
}

// ---------------- weight pre-pack to bf16 MFMA-B layout ---------------------
// W1t[l][n(128)][k(64)]: n<114,k<57 -> ew1[l][k][n]; k==57 -> eb1[l][n]; else 0
// W2t[l][n(64)][k(128)]: k<114 -> ew2[l][k][n]; k==114 -> eb2[l][n]; else 0
// CW1t[n(256)][k(64)]  : cw1[0][k][n]
__global__ void pack_kernel(const float* __restrict__ ew1, const float* __restrict__ eb1,
                            const float* __restrict__ ew2, const float* __restrict__ eb2,
                            const float* __restrict__ cw1, bf16_t* __restrict__ pw)
{
    int idx = blockIdx.x * blockDim.x + threadIdx.x;
    const int W1SZ = 128 * 64, W2SZ = 64 * 128;
    float v = 0.0f;
    if (idx < 2 * W1SZ) {
        int l = idx / W1SZ, r = idx - l * W1SZ;
        int n = r >> 6, k = r & 63;
        if (n < EH && k < EDGE_IN)      v = ew1[(l * EDGE_IN + k) * EH + n];
        else if (n < EH && k == EDGE_IN) v = eb1[l * EH + n];
        pw[idx] = (bf16_t)v;
    } else if (idx < 2 * W1SZ + 2 * W2SZ) {
        int r0 = idx - 2 * W1SZ;
        int l = r0 / W2SZ, r = r0 - l * W2SZ;
        int n = r >> 7, k = r & 127;
        if (k < EH)       v = ew2[(l * EH + k) * MDIM + n];
        else if (k == EH) v = eb2[l * MDIM + n];
        pw[idx] = (bf16_t)v;
    } else if (idx < 2 * W1SZ + 2 * W2SZ + 256 * 64) {
        int r = idx - (2 * W1SZ + 2 * W2SZ);
        int n = r >> 6, k = r & 63;
        pw[idx] = (bf16_t)cw1[k * CH + n];
    }
}

// ---------------- CSR build --------------------------------------------------
__global__ void hist_kernel(const int* __restrict__ dst, int* __restrict__ deg)
{
    int e = blockIdx.x * blockDim.x + threadIdx.x;
    if (e < N_EDGES) atomicAdd(&deg[dst[e]], 1);
}

__global__ __launch_bounds__(1024)
void scan_kernel(const int* __restrict__ deg, int* __restrict__ cursor)
{
    __shared__ int part[1024];
    int t = threadIdx.x;
    const int PER = 49; // 49*1024 = 50176 >= 50000
    int base = t * PER;
    int s = 0;
    for (int i = 0; i < PER; i++) {
        int p = base + i;
        if (p < N_NODES) s += deg[p];
    }
    part[t] = s;
    __syncthreads();
    for (int off = 1; off < 1024; off <<= 1) {
        int add = (t >= off) ? part[t - off] : 0;
        __syncthreads();
        part[t] += add;
        __syncthreads();
    }
    int run = (t > 0) ? part[t - 1] : 0;
    for (int i = 0; i < PER; i++) {
        int p = base + i;
        if (p < N_NODES) { cursor[p] = run; run += deg[p]; }
    }
}

__global__ void scatter_kernel(const int* __restrict__ src, const int* __restrict__ dst,
                               int* __restrict__ cursor, int* __restrict__ srcs_s,
                               int* __restrict__ dsts_s)
{
    int e = blockIdx.x * blockDim.x + threadIdx.x;
    if (e >= N_EDGES) return;
    int d = dst[e];
    int pos = atomicAdd(&cursor[d], 1);
    srcs_s[pos] = src[e];
    dsts_s[pos] = d;
}

// ---------------- fused MFMA edge kernel ------------------------------------
// Block: 256 threads (4 waves), 128 edges (dst-sorted). Layouts:
//   R1 region (32KB): phase1 Ein bf16 [128][64] (swz), phase2 H1 bf16 [128][128] (swz),
//                     phase3 Mf32 f32 [128][64] (plain)
//   sMb (COOR): m bf16 [128][64] (swz) for GEMM3 A.
// Swizzle: 16B granule g at row r -> g ^ (r&7) (breaks 16-way ds_read_b128 conflicts).
// MFMA 16x16x32 bf16: A lane: row=l&15, k=(l>>4)*8+j ; B lane: col=l&15, k=(l>>4)*8+j ;
// D lane: col=l&15, row=(l>>4)*4+reg (guide §3, m89-verified).
template<int COOR>
__global__ __launch_bounds__(256, 2)
void edge_mfma(const float* __restrict__ feats, const float* __restrict__ coors,
               const int* __restrict__ srcs_s, const int* __restrict__ dsts_s,
               const bf16_t* __restrict__ W1t, const bf16_t* __restrict__ W2t,
               const bf16_t* __restrict__ CW1t, const float* __restrict__ cb1,
               const float* __restrict__ cw2, const float* __restrict__ cb2,
               float* __restrict__ m_i, float* __restrict__ cdelta)
{
    __shared__ __align__(16) char R1raw[ETILE * 128 * 2];
    __shared__ __align__(16) bf16_t sMb[COOR ? ETILE * 64 : 8];
    __shared__ float s_rel[COOR ? ETILE * 3 : 4];
    __shared__ int   s_dst[ETILE];
    bf16_t* R1 = (bf16_t*)R1raw;
    float*  Mf32 = (float*)R1raw;

    const int t = threadIdx.x;
    const int w = t >> 6;        // wave id
    const int l = t & 63;        // lane
    const int row0 = w * 32;     // wave's M stripe
    const int ebase = blockIdx.x * ETILE;

    // ---- gather: build Ein [128][64] bf16 swizzled -----
    {
        int e_loc = t >> 1, half = t & 1;
        int e = ebase + e_loc;
        if (half == 0) {
            int d = dsts_s[e];
            s_dst[e_loc] = d;
            const float4* fd = reinterpret_cast<const float4*>(feats + (size_t)d * EMB);
            #pragma unroll
            for (int g = 0; g < 3; g++) {
                float4 a = fd[g*2], b = fd[g*2+1];
                bf16x8 pk;
                pk[0]=(bf16_t)a.x; pk[1]=(bf16_t)a.y; pk[2]=(bf16_t)a.z; pk[3]=(bf16_t)a.w;
                pk[4]=(bf16_t)b.x; pk[5]=(bf16_t)b.y; pk[6]=(bf16_t)b.z; pk[7]=(bf16_t)b.w;
                int gs = g ^ (e_loc & 7);
                *(bf16x8*)&R1[e_loc * 64 + gs * 8] = pk;
            }
        } else {
            int s = srcs_s[e], d = dsts_s[e];
            const float4* fs = reinterpret_cast<const float4*>(feats + (size_t)s * EMB);
            #pragma unroll
            for (int g = 0; g < 3; g++) {
                float4 a = fs[g*2], b = fs[g*2+1];
                bf16x8 pk;
                pk[0]=(bf16_t)a.x; pk[1]=(bf16_t)a.y; pk[2]=(bf16_t)a.z; pk[3]=(bf16_t)a.w;
                pk[4]=(bf16_t)b.x; pk[5]=(bf16_t)b.y; pk[6]=(bf16_t)b.z; pk[7]=(bf16_t)b.w;
                int gs = (g + 3) ^ (e_loc & 7);
                *(bf16x8*)&R1[e_loc * 64 + gs * 8] = pk;
            }
            float rx = coors[s*3+0] - coors[d*3+0];
            float ry = coors[s*3+1] - coors[d*3+1];
            float rz = coors[s*3+2] - coors[d*3+2];
            float d2 = rx*rx + ry*ry + rz*rz;
            if (COOR) { s_rel[e_loc*3+0] = rx; s_rel[e_loc*3+1] = ry; s_rel[e_loc*3+2] = rz; }
            bf16x8 p6, p7;
            p6[0]=(bf16_t)sinf(d2);        p6[1]=(bf16_t)sinf(d2*0.5f);
            p6[2]=(bf16_t)sinf(d2*0.25f);  p6[3]=(bf16_t)sinf(d2*0.125f);
            p6[4]=(bf16_t)cosf(d2);        p6[5]=(bf16_t)cosf(d2*0.5f);
            p6[6]=(bf16_t)cosf(d2*0.25f);  p6[7]=(bf16_t)cosf(d2*0.125f);
            p7[0]=(bf16_t)d2; p7[1]=(bf16_t)1.0f;
            p7[2]=(bf16_t)0.f; p7[3]=(bf16_t)0.f; p7[4]=(bf16_t)0.f;
            p7[5]=(bf16_t)0.f; p7[6]=(bf16_t)0.f; p7[7]=(bf16_t)0.f;
            int g6 = 6 ^ (e_loc & 7), g7 = 7 ^ (e_loc & 7);
            *(bf16x8*)&R1[e_loc * 64 + g6 * 8] = p6;
            *(bf16x8*)&R1[e_loc * 64 + g7 * 8] = p7;
        }
    }
    __syncthreads();

    // ---- GEMM1: Ein[128][64] @ W1t -> H1[128][128] ----
    f32x4 acc[2][8];
    #pragma unroll
    for (int mt = 0; mt < 2; mt++)
        #pragma unroll
        for (int nt = 0; nt < 8; nt++) acc[mt][nt] = (f32x4){0.f,0.f,0.f,0.f};
    #pragma unroll
    for (int ks = 0; ks < 2; ks++) {
        bf16x8 a[2];
        #pragma unroll
        for (int mt = 0; mt < 2; mt++) {
            int r = row0 + mt*16 + (l & 15);
            int g = (ks*4 + (l >> 4)) ^ (r & 7);
            a[mt] = *(const bf16x8*)&R1[r*64 + g*8];
        }
        #pragma unroll
        for (int nt = 0; nt < 8; nt++) {
            int n = nt*16 + (l & 15);
            bf16x8 b = *(const bf16x8*)&W1t[n*64 + (ks*4 + (l >> 4))*8];
            acc[0][nt] = __builtin_amdgcn_mfma_f32_16x16x32_bf16(a[0], b, acc[0][nt], 0, 0, 0);
            acc[1][nt] = __builtin_amdgcn_mfma_f32_16x16x32_bf16(a[1], b, acc[1][nt], 0, 0, 0);
        }
    }
    __syncthreads();
    // write H1 = silu(acc); col 114 = 1.0 (GEMM2 bias slot)
    #pragma unroll
    for (int mt = 0; mt < 2; mt++)
        #pragma unroll
        for (int nt = 0; nt < 8; nt++)
            #pragma unroll
            for (int r4 = 0; r4 < 4; r4++) {
                int row = row0 + mt*16 + (l >> 4)*4 + r4;
                int col = nt*16 + (l & 15);
                float hv = siluf(acc[mt][nt][r4]);
                if (col == EH) hv = 1.0f;
                int g = (col >> 3) ^ (row & 7);
                R1[row*128 + g*8 + (col & 7)] = (bf16_t)hv;
            }
    __syncthreads();

    // ---- GEMM2: H1[128][128] @ W2t -> M[128][64] ----
    f32x4 acc2[2][4];
    #pragma unroll
    for (int mt = 0; mt < 2; mt++)
        #pragma unroll
        for (int nt = 0; nt < 4; nt++) acc2[mt][nt] = (f32x4){0.f,0.f,0.f,0.f};
    #pragma unroll
    for (int ks = 0; ks < 4; ks++) {
        bf16x8 a[2];
        #pragma unroll
        for (int mt = 0; mt < 2; mt++) {
            int r = row0 + mt*16 + (l & 15);
            int g = (ks*4 + (l >> 4)) ^ (r & 7);
            a[mt] = *(const bf16x8*)&R1[r*128 + g*8];
        }
        #pragma unroll
        for (int nt = 0; nt < 4; nt++) {
            int n = nt*16 + (l & 15);
            bf16x8 b = *(const bf16x8*)&W2t[n*128 + (ks*4 + (l >> 4))*8];
            acc2[0][nt] = __builtin_amdgcn_mfma_f32_16x16x32_bf16(a[0], b, acc2[0][nt], 0, 0, 0);
            acc2[1][nt] = __builtin_amdgcn_mfma_f32_16x16x32_bf16(a[1], b, acc2[1][nt], 0, 0, 0);
        }
    }
    __syncthreads();
    // write Mf32 (plain) + sMb (bf16 swizzled, COOR only)
    #pragma unroll
    for (int mt = 0; mt < 2; mt++)
        #pragma unroll
        for (int nt = 0; nt < 4; nt++)
            #pragma unroll
            for (int r4 = 0; r4 < 4; r4++) {
                int row = row0 + mt*16 + (l >> 4)*4 + r4;
                int col = nt*16 + (l & 15);
                float mv = siluf(acc2[mt][nt][r4]);
                Mf32[row*64 + col] = mv;
                if (COOR) {
                    int g = (col >> 3) ^ (row & 7);
                    sMb[row*64 + g*8 + (col & 7)] = (bf16_t)mv;
                }
            }
    __syncthreads();

    // ---- m_i run-reduction (dst-sorted rows) ----
    {
        int col = t & 63;
        int wbase = (t >> 6) * 32;
        int cur = s_dst[wbase];
        float run = 0.f;
        for (int i = 0; i < 32; i++) {
            int row = wbase + i;
            int d = s_dst[row];
            float v = Mf32[row*64 + col];
            if (d != cur) { atomicAdd(&m_i[(size_t)cur*64 + col], run); run = 0.f; cur = d; }
            run += v;
        }
        atomicAdd(&m_i[(size_t)cur*64 + col], run);
    }

    // ---- GEMM3 + coor scatter (layer 0 only) ----
    if (COOR) {
        f32x4 csum[2];
        csum[0] = (f32x4){0.f,0.f,0.f,0.f};
        csum[1] = (f32x4){0.f,0.f,0.f,0.f};
        #pragma unroll
        for (int half = 0; half < 2; half++) {
            f32x4 acc3[2][8];
            #pragma unroll
            for (int mt = 0; mt < 2; mt++)
                #pragma unroll
                for (int nt = 0; nt < 8; nt++) acc3[mt][nt] = (f32x4){0.f,0.f,0.f,0.f};
            #pragma unroll
            for (int ks = 0; ks < 2; ks++) {
                bf16x8 a[2];
                #pragma unroll
                for (int mt = 0; mt < 2; mt++) {
                    int r = row0 + mt*16 + (l & 15);
                    int g = (ks*4 + (l >> 4)) ^ (r & 7);
                    a[mt] = *(const bf16x8*)&sMb[r*64 + g*8];
                }
                #pragma unroll
                for (int nt = 0; nt < 8; nt++) {
                    int n = half*128 + nt*16 + (l & 15);
                    bf16x8 b = *(const bf16x8*)&CW1t[n*64 + (ks*4 + (l >> 4))*8];
                    acc3[0][nt] = __builtin_amdgcn_mfma_f32_16x16x32_bf16(a[0], b, acc3[0][nt], 0, 0, 0);
                    acc3[1][nt] = __builtin_amdgcn_mfma_f32_16x16x32_bf16(a[1], b, acc3[1][nt], 0, 0, 0);
                }
            }
            #pragma unroll
            for (int mt = 0; mt < 2; mt++)
                #pragma unroll
                for (int nt = 0; nt < 8; nt++) {
                    int n = half*128 + nt*16 + (l & 15);
                    float c1 = cb1[n], w2v = cw2[n];
                    #pragma unroll
                    for (int r4 = 0; r4 < 4; r4++)
                        csum[mt][r4] = fmaf(siluf(acc3[mt][nt][r4] + c1), w2v, csum[mt][r4]);
                }
        }
        // reduce over the 16 lanes sharing (l>>4)
        #pragma unroll
        for (int mask = 1; mask < 16; mask <<= 1) {
            #pragma unroll
            for (int mt = 0; mt < 2; mt++)
                #pragma unroll
                for (int r4 = 0; r4 < 4; r4++)
                    csum[mt][r4] += __shfl_xor(csum[mt][r4], mask);
        }
        if ((l & 15) == 0) {
            float cb2v = cb2[0];
            #pragma unroll
            for (int mt = 0; mt < 2; mt++)
                #pragma unroll
                for (int r4 = 0; r4 < 4; r4++) {
                    int row = row0 + mt*16 + (l >> 4)*4 + r4;
                    float cacc = csum[mt][r4] + cb2v;
                    int d = s_dst[row];
                    atomicAdd(&cdelta[d*3+0], cacc * s_rel[row*3+0]);
                    atomicAdd(&cdelta[d*3+1], cacc * s_rel[row*3+1]);
                    atomicAdd(&cdelta[d*3+2], cacc * s_rel[row*3+2]);
                }
        }
    }
}

// ---------------- node kernel: feats_out = feats + MLP([feats, m_i]) --------
__global__ __launch_bounds__(256)
void node_kernel(const float* __restrict__ feats, const float* __restrict__ m_i,
                 const float* __restrict__ nw1, const float* __restrict__ nb1,
                 const float* __restrict__ nw2, const float* __restrict__ nb2,
                 float* __restrict__ fout)
{
    __shared__ float s_w1t[NH * NIN]; // [k][i]
    __shared__ float s_b1[NH];
    __shared__ float s_w2[NH * EMB];  // [k][j]
    __shared__ float s_b2[EMB];
    const int tid = threadIdx.x;
    for (int idx = tid; idx < NH * NIN; idx += 256) {
        int k = idx / NIN, i = idx - k * NIN;
        s_w1t[idx] = nw1[i * NH + k];
    }
    for (int idx = tid; idx < NH * EMB; idx += 256) s_w2[idx] = nw2[idx];
    if (tid < NH) s_b1[tid] = nb1[tid];
    if (tid < EMB) s_b2[tid] = nb2[tid];
    __syncthreads();

    int n = blockIdx.x * 256 + tid;
    if (n >= N_NODES) return;

    float in[NIN];
    const float4* fp = reinterpret_cast<const float4*>(feats + (size_t)n * EMB);
    #pragma unroll
    for (int q = 0; q < 6; q++) {
        float4 v = fp[q];
        in[q*4] = v.x; in[q*4+1] = v.y; in[q*4+2] = v.z; in[q*4+3] = v.w;
    }
    const float4* mp = reinterpret_cast<const float4*>(m_i + (size_t)n * MDIM);
    #pragma unroll
    for (int q = 0; q < 16; q++) {
        float4 v = mp[q];
        in[EMB+q*4] = v.x; in[EMB+q*4+1] = v.y; in[EMB+q*4+2] = v.z; in[EMB+q*4+3] = v.w;
    }
    float o[EMB];
    #pragma unroll
    for (int j = 0; j < EMB; j++) o[j] = in[j] + s_b2[j];
    for (int k = 0; k < NH; k++) {
        const float* w1 = &s_w1t[k * NIN];
        float a0 = 0.f, a1 = 0.f, a2 = 0.f, a3 = 0.f;
        #pragma unroll
        for (int i = 0; i < NIN; i += 4) {
            a0 = fmaf(in[i],   w1[i],   a0);
            a1 = fmaf(in[i+1], w1[i+1], a1);
            a2 = fmaf(in[i+2], w1[i+2], a2);
            a3 = fmaf(in[i+3], w1[i+3], a3);
        }
        float h = siluf(s_b1[k] + ((a0 + a1) + (a2 + a3)));
        const float* w2 = &s_w2[k * EMB];
        #pragma unroll
        for (int j = 0; j < EMB; j++) o[j] = fmaf(h, w2[j], o[j]);
    }
    float4* dst = reinterpret_cast<float4*>(fout + (size_t)n * EMB);
    #pragma unroll
    for (int q = 0; q < 6; q++) dst[q] = make_float4(o[q*4], o[q*4+1], o[q*4+2], o[q*4+3]);
}

// ---------------- coors update ------------------------------------------------
__global__ void coor_kernel(const float* __restrict__ pos, const float* __restrict__ cdelta,
                            float* __restrict__ out)
{
    int i = blockIdx.x * blockDim.x + threadIdx.x;
    if (i < N_NODES * 3) out[i] = pos[i] + cdelta[i];
}

// ---------------- FFNN layer 0 ------------------------------------------------
__global__ __launch_bounds__(256)
void ffnn0_kernel(const float* __restrict__ f0, const float* __restrict__ f1,
                  const float* __restrict__ f2, const float* __restrict__ w,
                  const float* __restrict__ b, float* __restrict__ hout,
                  int n0, int nmax)
{
    __shared__ float s_xt[FIN * NPB]; // [i][nn]
    int lbase = blockIdx.x * NPB;
    for (int idx = threadIdx.x; idx < FIN * NPB; idx += 256) {
        int nn = idx / FIN, i = idx - nn * FIN;
        int n = n0 + lbase + nn;
        float v = 0.f;
        if (n < nmax) {
            float s;
            if (i < 24)      s = f0[(size_t)n * EMB + i];
            else if (i < 48) s = f1[(size_t)n * EMB + (i - 24)];
            else             s = f2[(size_t)n * EMB + (i - 48)];
            v = siluf(s);
        }
        s_xt[i * NPB + nn] = v;
    }
    __syncthreads();
    int j = threadIdx.x;
    float acc[NPB];
    #pragma unroll
    for (int nn = 0; nn < NPB; nn++) acc[nn] = b[j];
    for (int i = 0; i < FIN; i++) {
        float wv = w[i * MLP + j];
        const float* xr = &s_xt[i * NPB];
        #pragma unroll
        for (int nn = 0; nn < NPB; nn++) acc[nn] = fmaf(xr[nn], wv, acc[nn]);
    }
    #pragma unroll
    for (int nn = 0; nn < NPB; nn++) {
        int n = n0 + lbase + nn;
        if (n < nmax) hout[(size_t)(lbase + nn) * MLP + j] = siluf(acc[nn]);
    }
}

// ---------------- FFNN mid / pool layers -------------------------------------
template<int POOL>
__global__ __launch_bounds__(256)
void ffnn_mid_kernel(const float* __restrict__ hin, const float* __restrict__ w,
                     const float* __restrict__ b, float* __restrict__ hout,
                     float* __restrict__ pooled, const int* __restrict__ batch,
                     int n0, int nmax)
{
    __shared__ float s_xt[MLP * NPB]; // 16 KB, [i][nn]
    int lbase = blockIdx.x * NPB;
    for (int idx = threadIdx.x; idx < MLP * NPB; idx += 256) {
        int nn = idx >> 8, i = idx & 255;
        int n = n0 + lbase + nn;
        s_xt[i * NPB + nn] = (n < nmax) ? hin[(size_t)(lbase + nn) * MLP + i] : 0.f;
    }
    __syncthreads();
    int j = threadIdx.x;
    float acc[NPB];
    #pragma unroll
    for (int nn = 0; nn < NPB; nn++) acc[nn] = b[j];
    for (int i = 0; i < MLP; i++) {
        float wv = w[i * MLP + j];
        const float* xr = &s_xt[i * NPB];
        #pragma unroll
        for (int nn = 0; nn < NPB; nn++) acc[nn] = fmaf(xr[nn], wv, acc[nn]);
    }
    if (!POOL) {
        #pragma unroll
        for (int nn = 0; nn < NPB; nn++) {
            int n = n0 + lbase + nn;
            if (n < nmax) hout[(size_t)(lbase + nn) * MLP + j] = siluf(acc[nn]);
        }
    } else {
        float runsum = 0.f;
        int curb = -1;
        #pragma unroll
        for (int nn = 0; nn < NPB; nn++) {
            int n = n0 + lbase + nn;
            if (n < nmax) {
                int bb = batch[n];
                if (bb != curb) {
                    if (curb >= 0) atomicAdd(&pooled[curb * MLP + j], runsum);
                    runsum = 0.f; curb = bb;
                }
                runsum += siluf(acc[nn]);
            }
        }
        if (curb >= 0) atomicAdd(&pooled[curb * MLP + j], runsum);
    }
}

// ---------------- final: sigmoid((pooled/cnt) @ fow + fob) -------------------
__global__ void final_kernel(const float* __restrict__ pooled, const float* __restrict__ cnt,
                             const float* __restrict__ fow, const float* __restrict__ fob,
                             float* __restrict__ out)
{
    int t = threadIdx.x;  // 256 = 64 graphs * 4 outputs
    int bg = t >> 2, o = t & 3;
    float c = fmaxf(cnt[bg], 1.0f);
    float acc = 0.f;
    for (int i = 0; i < MLP; i++) acc = fmaf(pooled[bg * MLP + i], fow[i * 4 + o], acc);
    acc = acc / c + fob[o];
    out[t] = 1.0f / (1.0f + __expf(-acc));
}

extern "C" void kernel_launch(void* const* d_in, const int* in_sizes, int n_in,
                              void* d_out, int out_size, void* d_ws, size_t ws_size,
                              hipStream_t stream)
{
    const int*   z     = (const int*)  d_in[0];
    const float* pos   = (const float*)d_in[1];
    const int*   eidx  = (const int*)  d_in[2];
    const int*   batch = (const int*)  d_in[3];
    const float* embt  = (const float*)d_in[4];
    const float* embw  = (const float*)d_in[5];
    const float* embb  = (const float*)d_in[6];
    const float* ew1   = (const float*)d_in[7];
    const float* eb1   = (const float*)d_in[8];
    const float* ew2   = (const float*)d_in[9];
    const float* eb2   = (const float*)d_in[10];
    const float* cw1   = (const float*)d_in[11];
    const float* cb1   = (const float*)d_in[12];
    const float* cw2   = (const float*)d_in[13];
    const float* cb2   = (const float*)d_in[14];
    const float* nw1   = (const float*)d_in[15];
    const float* nb1   = (const float*)d_in[16];
    const float* nw2   = (const float*)d_in[17];
    const float* nb2   = (const float*)d_in[18];
    const float* f0w   = (const float*)d_in[19];
    const float* f0b   = (const float*)d_in[20];
    const float* f1w   = (const float*)d_in[21];
    const float* f1b   = (const float*)d_in[22];
    const float* f2w   = (const float*)d_in[23];
    const float* f2b   = (const float*)d_in[24];
    const float* fow   = (const float*)d_in[25];
    const float* fob   = (const float*)d_in[26];

    float* ws     = (float*)d_ws;
    float* f0     = ws;                                   // 1,200,000
    float* f1v    = f0 + (size_t)N_NODES * EMB;
    float* f2v    = f1v + (size_t)N_NODES * EMB;
    float* coorsA = f2v + (size_t)N_NODES * EMB;          // 150,000
    float* cdelta = coorsA + N_NODES * 3;                 // 150,000
    float* m_i    = cdelta + N_NODES * 3;                 // 3,200,000
    float* hA     = m_i + (size_t)N_NODES * MDIM;         // CHUNK*256
    float* hB     = hA + (size_t)CHUNK * MLP;
    float* pooled = hB + (size_t)CHUNK * MLP;             // 16,384
    float* cnt    = pooled + N_GRAPHS * MLP;              // 64
    int*   deg    = (int*)(cnt + N_GRAPHS);               // 50,000
    int*   cursor = deg + N_NODES;                        // 50,000
    int*   srcs_s = cursor + N_NODES;                     // 800,000
    int*   dsts_s = srcs_s + N_EDGES;                     // 800,000
    bf16_t* packw = (bf16_t*)(dsts_s + N_EDGES);          // 49,152 bf16
    bf16_t* W1t0  = packw;
    bf16_t* W1t1  = W1t0 + 128*64;
    bf16_t* W2t0  = W1t1 + 128*64;
    bf16_t* W2t1  = W2t0 + 64*128;
    bf16_t* CW1t  = W2t1 + 64*128;

    hipMemsetAsync(cdelta, 0, N_NODES * 3 * sizeof(float), stream);
    hipMemsetAsync(m_i, 0, (size_t)N_NODES * MDIM * sizeof(float), stream);
    hipMemsetAsync(pooled, 0, (N_GRAPHS * MLP + N_GRAPHS) * sizeof(float), stream);
    hipMemsetAsync(deg, 0, N_NODES * sizeof(int), stream);

    // CSR build (dst-sorted edge list)
    const int* e_src = eidx;
    const int* e_dst = eidx + N_EDGES;
    pack_kernel<<<(49152 + 255) / 256, 256, 0, stream>>>(ew1, eb1, ew2, eb2, cw1, packw);
    hist_kernel<<<(N_EDGES + 255) / 256, 256, 0, stream>>>(e_dst, deg);
    scan_kernel<<<1, 1024, 0, stream>>>(deg, cursor);
    scatter_kernel<<<(N_EDGES + 255) / 256, 256, 0, stream>>>(e_src, e_dst, cursor, srcs_s, dsts_s);

    embed_kernel<<<(N_NODES + 255) / 256, 256, 0, stream>>>(z, embt, embw, embb, batch, f0, cnt);

    const int EBLK = N_EDGES / ETILE; // 6250 exact
    // layer 0 (with coor update)
    edge_mfma<1><<<EBLK, 256, 0, stream>>>(f0, pos, srcs_s, dsts_s,
        W1t0, W2t0, CW1t, cb1, cw2, cb2, m_i, cdelta);
    node_kernel<<<(N_NODES + 255) / 256, 256, 0, stream>>>(f0, m_i, nw1, nb1, nw2, nb2, f1v);
    coor_kernel<<<(N_NODES * 3 + 255) / 256, 256, 0, stream>>>(pos, cdelta, coorsA);
    hipMemsetAsync(m_i, 0, (size_t)N_NODES * MDIM * sizeof(float), stream);
    // layer 1 (coors output dead downstream)
    edge_mfma<0><<<EBLK, 256, 0, stream>>>(f1v, coorsA, srcs_s, dsts_s,
        W1t1, W2t1, CW1t, cb1, cw2, cb2, m_i, nullptr);
    node_kernel<<<(N_NODES + 255) / 256, 256, 0, stream>>>(f1v, m_i,
        nw1 + NIN * NH, nb1 + NH, nw2 + NH * EMB, nb2 + EMB, f2v);

    // FFNN, chunked through ws ping-pong
    for (int n0 = 0; n0 < N_NODES; n0 += CHUNK) {
        int nc = (N_NODES - n0 < CHUNK) ? (N_NODES - n0) : CHUNK;
        int blocks = (nc + NPB - 1) / NPB;
        ffnn0_kernel<<<blocks, 256, 0, stream>>>(f0, f1v, f2v, f0w, f0b, hA, n0, N_NODES);
        ffnn_mid_kernel<0><<<blocks, 256, 0, stream>>>(hA, f1w, f1b, hB, nullptr, nullptr, n0, N_NODES);
        ffnn_mid_kernel<1><<<blocks, 256, 0, stream>>>(hB, f2w, f2b, nullptr, pooled, batch, n0, N_NODES);
    }

    final_kernel<<<1, 256, 0, stream>>>(pooled, cnt, fow, fob, (float*)d_out);
}

// Round 3
// 1342.491 us; speedup vs baseline: 5.1760x; 1.0180x over previous
//
#include <hip/hip_runtime.h>
#include <hip/hip_bf16.h>

#define N_NODES  50000
#define N_EDGES  800000
#define N_GRAPHS 64
#define EMB      24
#define MDIM     64
#define EDGE_IN  57
#define EH       114   // EDGE_IN*2
#define CH       256   // M_DIM*4
#define NIN      88    // EMB+MDIM
#define NH       48    // EMB*2
#define MLP      256
#define ETILE    64
#define NTILE    64

typedef __bf16 bf16_t;
typedef __bf16 bf16x8 __attribute__((ext_vector_type(8)));
typedef float  f32x4  __attribute__((ext_vector_type(4)));

__device__ __forceinline__ float siluf(float x) {
    return x * __builtin_amdgcn_rcpf(1.0f + __expf(-x));
}

// ---------------- embedding: feats0 = emb_table[z] @ emb_w + emb_b ----------
__global__ void embed_kernel(const int* __restrict__ z, const float* __restrict__ table,
                             const float* __restrict__ w, const float* __restrict__ b,
                             const int* __restrict__ batch, float* __restrict__ f0,
                             float* __restrict__ cnt)
{
    int n = blockIdx.x * blockDim.x + threadIdx.x;
    if (n >= N_NODES) return;
    float r[EMB];
    const float4* tr = reinterpret_cast<const float4*>(table + z[n] * EMB);
    #pragma unroll
    for (int q = 0; q < 6; q++) {
        float4 v = tr[q];
        r[q*4] = v.x; r[q*4+1] = v.y; r[q*4+2] = v.z; r[q*4+3] = v.w;
    }
    float o[EMB];
    #pragma unroll
    for (int j = 0; j < EMB; j++) o[j] = b[j];
    #pragma unroll
    for (int i = 0; i < EMB; i++) {
        #pragma unroll
        for (int j = 0; j < EMB; j++) o[j] = fmaf(r[i], w[i*EMB + j], o[j]);
    }
    float4* dst = reinterpret_cast<float4*>(f0 + (size_t)n * EMB);
    #pragma unroll
    for (int q = 0; q < 6; q++) dst[q] = make_float4(o[q*4], o[q*4+1], o[q*4+2], o[q*4+3]);
    atomicAdd(&cnt[batch[n]], 1.0f);
}

// ---------------- weight pre-pack to bf16 MFMA-B layout ---------------------
// W1t[l][n(128)][k(64)] ; W2t[l][n(64)][k(128)] ; CW1t[n(256)][k(64)]
// W0p[n(256)][k(128)]   ; W1p[n(256)][k(256)]   ; W2p[n(256)][k(256)]
#define PK_W1   (128*64)
#define PK_W2   (64*128)
#define PK_CW   (256*64)
#define PK_F0   (256*128)
#define PK_FM   (256*256)
#define PK_TOT  (2*PK_W1 + 2*PK_W2 + PK_CW + PK_F0 + 2*PK_FM)
__global__ void pack_kernel(const float* __restrict__ ew1, const float* __restrict__ eb1,
                            const float* __restrict__ ew2, const float* __restrict__ eb2,
                            const float* __restrict__ cw1, const float* __restrict__ f0w,
                            const float* __restrict__ f1w, const float* __restrict__ f2w,
                            bf16_t* __restrict__ pw)
{
    int idx = blockIdx.x * blockDim.x + threadIdx.x;
    if (idx >= PK_TOT) return;
    float v = 0.0f;
    if (idx < 2 * PK_W1) {
        int l = idx / PK_W1, r = idx - l * PK_W1;
        int n = r >> 6, k = r & 63;
        if (n < EH && k < EDGE_IN)       v = ew1[(l * EDGE_IN + k) * EH + n];
        else if (n < EH && k == EDGE_IN) v = eb1[l * EH + n];
    } else if (idx < 2 * PK_W1 + 2 * PK_W2) {
        int r0 = idx - 2 * PK_W1;
        int l = r0 / PK_W2, r = r0 - l * PK_W2;
        int n = r >> 7, k = r & 127;
        if (k < EH)       v = ew2[(l * EH + k) * MDIM + n];
        else if (k == EH) v = eb2[l * MDIM + n];
    } else if (idx < 2 * PK_W1 + 2 * PK_W2 + PK_CW) {
        int r = idx - (2 * PK_W1 + 2 * PK_W2);
        int n = r >> 6, k = r & 63;
        v = cw1[k * CH + n];
    } else if (idx < 2 * PK_W1 + 2 * PK_W2 + PK_CW + PK_F0) {
        int r = idx - (2 * PK_W1 + 2 * PK_W2 + PK_CW);
        int n = r >> 7, k = r & 127;
        if (k < 72) v = f0w[k * MLP + n];
    } else {
        int r0 = idx - (2 * PK_W1 + 2 * PK_W2 + PK_CW + PK_F0);
        int l = r0 / PK_FM, r = r0 - l * PK_FM;
        int n = r >> 8, k = r & 255;
        v = (l == 0) ? f1w[k * MLP + n] : f2w[k * MLP + n];
    }
    pw[idx] = (bf16_t)v;
}

// ---------------- CSR build --------------------------------------------------
__global__ void hist_kernel(const int* __restrict__ dst, int* __restrict__ deg)
{
    int e = blockIdx.x * blockDim.x + threadIdx.x;
    if (e < N_EDGES) atomicAdd(&deg[dst[e]], 1);
}

__global__ __launch_bounds__(1024)
void scan_kernel(const int* __restrict__ deg, int* __restrict__ cursor)
{
    __shared__ int part[1024];
    int t = threadIdx.x;
    const int PER = 49;
    int base = t * PER;
    int s = 0;
    for (int i = 0; i < PER; i++) {
        int p = base + i;
        if (p < N_NODES) s += deg[p];
    }
    part[t] = s;
    __syncthreads();
    for (int off = 1; off < 1024; off <<= 1) {
        int add = (t >= off) ? part[t - off] : 0;
        __syncthreads();
        part[t] += add;
        __syncthreads();
    }
    int run = (t > 0) ? part[t - 1] : 0;
    for (int i = 0; i < PER; i++) {
        int p = base + i;
        if (p < N_NODES) { cursor[p] = run; run += deg[p]; }
    }
}

__global__ void scatter_kernel(const int* __restrict__ src, const int* __restrict__ dst,
                               int* __restrict__ cursor, int* __restrict__ srcs_s,
                               int* __restrict__ dsts_s)
{
    int e = blockIdx.x * blockDim.x + threadIdx.x;
    if (e >= N_EDGES) return;
    int d = dst[e];
    int pos = atomicAdd(&cursor[d], 1);
    srcs_s[pos] = src[e];
    dsts_s[pos] = d;
}

// ---------------- fused MFMA edge kernel (ETILE=64, 4 waves, 16 rows/wave) --
// LDS union: phase1 Ein bf16 [64][64] (8KB, swz) -> phase2 H1 bf16 [64][128]
// (16KB, swz) -> phase3 Mf32 f32 [64][64] (16KB, plain). sMb (COOR) separate.
// Swizzle: 16B granule g at row r -> g ^ (r&7).
template<int COOR>
__global__ __launch_bounds__(256, 6)
void edge_mfma(const float* __restrict__ feats, const float* __restrict__ coors,
               const int* __restrict__ srcs_s, const int* __restrict__ dsts_s,
               const bf16_t* __restrict__ W1t, const bf16_t* __restrict__ W2t,
               const bf16_t* __restrict__ CW1t, const float* __restrict__ cb1,
               const float* __restrict__ cw2, const float* __restrict__ cb2,
               float* __restrict__ m_i, float* __restrict__ cdelta)
{
    __shared__ __align__(16) char R1raw[ETILE * 128 * 2];       // 16KB
    __shared__ __align__(16) bf16_t sMb[COOR ? ETILE * 64 : 8]; // 8KB (COOR)
    __shared__ float s_rel[COOR ? ETILE * 3 : 4];
    __shared__ int   s_dst[ETILE];
    bf16_t* R1 = (bf16_t*)R1raw;
    float*  Mf32 = (float*)R1raw;

    const int t = threadIdx.x;
    const int w = t >> 6;
    const int l = t & 63;
    const int row0 = w * 16;
    const int ebase = blockIdx.x * ETILE;

    // ---- gather: 4 threads per edge ----
    {
        int e_loc = t >> 2, part = t & 3;
        int e = ebase + e_loc;
        int s = srcs_s[e], d = dsts_s[e];
        if (part == 0) {
            s_dst[e_loc] = d;
            const float4* fd = reinterpret_cast<const float4*>(feats + (size_t)d * EMB);
            #pragma unroll
            for (int g = 0; g < 3; g++) {
                float4 a = fd[g*2], b = fd[g*2+1];
                bf16x8 pk;
                pk[0]=(bf16_t)a.x; pk[1]=(bf16_t)a.y; pk[2]=(bf16_t)a.z; pk[3]=(bf16_t)a.w;
                pk[4]=(bf16_t)b.x; pk[5]=(bf16_t)b.y; pk[6]=(bf16_t)b.z; pk[7]=(bf16_t)b.w;
                *(bf16x8*)&R1[e_loc * 64 + (g ^ (e_loc & 7)) * 8] = pk;
            }
        } else if (part == 1) {
            const float4* fs = reinterpret_cast<const float4*>(feats + (size_t)s * EMB);
            #pragma unroll
            for (int g = 0; g < 3; g++) {
                float4 a = fs[g*2], b = fs[g*2+1];
                bf16x8 pk;
                pk[0]=(bf16_t)a.x; pk[1]=(bf16_t)a.y; pk[2]=(bf16_t)a.z; pk[3]=(bf16_t)a.w;
                pk[4]=(bf16_t)b.x; pk[5]=(bf16_t)b.y; pk[6]=(bf16_t)b.z; pk[7]=(bf16_t)b.w;
                *(bf16x8*)&R1[e_loc * 64 + ((g + 3) ^ (e_loc & 7)) * 8] = pk;
            }
        } else {
            float rx = coors[s*3+0] - coors[d*3+0];
            float ry = coors[s*3+1] - coors[d*3+1];
            float rz = coors[s*3+2] - coors[d*3+2];
            float d2 = rx*rx + ry*ry + rz*rz;
            if (part == 2) {
                if (COOR) { s_rel[e_loc*3+0] = rx; s_rel[e_loc*3+1] = ry; s_rel[e_loc*3+2] = rz; }
                bf16x8 p6;
                p6[0]=(bf16_t)sinf(d2);        p6[1]=(bf16_t)sinf(d2*0.5f);
                p6[2]=(bf16_t)sinf(d2*0.25f);  p6[3]=(bf16_t)sinf(d2*0.125f);
                p6[4]=(bf16_t)cosf(d2);        p6[5]=(bf16_t)cosf(d2*0.5f);
                p6[6]=(bf16_t)cosf(d2*0.25f);  p6[7]=(bf16_t)cosf(d2*0.125f);
                *(bf16x8*)&R1[e_loc * 64 + (6 ^ (e_loc & 7)) * 8] = p6;
            } else {
                bf16x8 p7;
                p7[0]=(bf16_t)d2; p7[1]=(bf16_t)1.0f;
                p7[2]=(bf16_t)0.f; p7[3]=(bf16_t)0.f; p7[4]=(bf16_t)0.f;
                p7[5]=(bf16_t)0.f; p7[6]=(bf16_t)0.f; p7[7]=(bf16_t)0.f;
                *(bf16x8*)&R1[e_loc * 64 + (7 ^ (e_loc & 7)) * 8] = p7;
            }
        }
    }
    __syncthreads();

    // ---- GEMM1: Ein[64][64] @ W1t -> H1[64][128] ----
    f32x4 acc[8];
    #pragma unroll
    for (int nt = 0; nt < 8; nt++) acc[nt] = (f32x4){0.f,0.f,0.f,0.f};
    #pragma unroll
    for (int ks = 0; ks < 2; ks++) {
        int r = row0 + (l & 15);
        bf16x8 a = *(const bf16x8*)&R1[r*64 + ((ks*4 + (l >> 4)) ^ (r & 7))*8];
        #pragma unroll
        for (int nt = 0; nt < 8; nt++) {
            int n = nt*16 + (l & 15);
            bf16x8 b = *(const bf16x8*)&W1t[n*64 + (ks*4 + (l >> 4))*8];
            acc[nt] = __builtin_amdgcn_mfma_f32_16x16x32_bf16(a, b, acc[nt], 0, 0, 0);
        }
    }
    __syncthreads();
    // write H1 = silu(acc); col 114 = 1.0 (GEMM2 bias slot)
    #pragma unroll
    for (int nt = 0; nt < 8; nt++)
        #pragma unroll
        for (int r4 = 0; r4 < 4; r4++) {
            int row = row0 + (l >> 4)*4 + r4;
            int col = nt*16 + (l & 15);
            float hv = siluf(acc[nt][r4]);
            if (col == EH) hv = 1.0f;
            R1[row*128 + ((col >> 3) ^ (row & 7))*8 + (col & 7)] = (bf16_t)hv;
        }
    __syncthreads();

    // ---- GEMM2: H1[64][128] @ W2t -> M[64][64] ----
    f32x4 acc2[4];
    #pragma unroll
    for (int nt = 0; nt < 4; nt++) acc2[nt] = (f32x4){0.f,0.f,0.f,0.f};
    #pragma unroll
    for (int ks = 0; ks < 4; ks++) {
        int r = row0 + (l & 15);
        bf16x8 a = *(const bf16x8*)&R1[r*128 + ((ks*4 + (l >> 4)) ^ (r & 7))*8];
        #pragma unroll
        for (int nt = 0; nt < 4; nt++) {
            int n = nt*16 + (l & 15);
            bf16x8 b = *(const bf16x8*)&W2t[n*128 + (ks*4 + (l >> 4))*8];
            acc2[nt] = __builtin_amdgcn_mfma_f32_16x16x32_bf16(a, b, acc2[nt], 0, 0, 0);
        }
    }
    __syncthreads();
    #pragma unroll
    for (int nt = 0; nt < 4; nt++)
        #pragma unroll
        for (int r4 = 0; r4 < 4; r4++) {
            int row = row0 + (l >> 4)*4 + r4;
            int col = nt*16 + (l & 15);
            float mv = siluf(acc2[nt][r4]);
            Mf32[row*64 + col] = mv;
            if (COOR) sMb[row*64 + ((col >> 3) ^ (row & 7))*8 + (col & 7)] = (bf16_t)mv;
        }
    __syncthreads();

    // ---- m_i run-reduction (dst-sorted rows; 16-row groups) ----
    {
        int col = t & 63;
        int gb = (t >> 6) * 16;
        int cur = s_dst[gb];
        float run = 0.f;
        for (int i = 0; i < 16; i++) {
            int row = gb + i;
            int d = s_dst[row];
            float v = Mf32[row*64 + col];
            if (d != cur) { atomicAdd(&m_i[(size_t)cur*64 + col], run); run = 0.f; cur = d; }
            run += v;
        }
        atomicAdd(&m_i[(size_t)cur*64 + col], run);
    }

    // ---- GEMM3 + coor scatter (layer 0 only) ----
    if (COOR) {
        f32x4 csum = (f32x4){0.f,0.f,0.f,0.f};
        #pragma unroll
        for (int half = 0; half < 2; half++) {
            f32x4 acc3[8];
            #pragma unroll
            for (int nt = 0; nt < 8; nt++) acc3[nt] = (f32x4){0.f,0.f,0.f,0.f};
            #pragma unroll
            for (int ks = 0; ks < 2; ks++) {
                int r = row0 + (l & 15);
                bf16x8 a = *(const bf16x8*)&sMb[r*64 + ((ks*4 + (l >> 4)) ^ (r & 7))*8];
                #pragma unroll
                for (int nt = 0; nt < 8; nt++) {
                    int n = half*128 + nt*16 + (l & 15);
                    bf16x8 b = *(const bf16x8*)&CW1t[n*64 + (ks*4 + (l >> 4))*8];
                    acc3[nt] = __builtin_amdgcn_mfma_f32_16x16x32_bf16(a, b, acc3[nt], 0, 0, 0);
                }
            }
            #pragma unroll
            for (int nt = 0; nt < 8; nt++) {
                int n = half*128 + nt*16 + (l & 15);
                float c1 = cb1[n], w2v = cw2[n];
                #pragma unroll
                for (int r4 = 0; r4 < 4; r4++)
                    csum[r4] = fmaf(siluf(acc3[nt][r4] + c1), w2v, csum[r4]);
            }
        }
        #pragma unroll
        for (int mask = 1; mask < 16; mask <<= 1)
            #pragma unroll
            for (int r4 = 0; r4 < 4; r4++)
                csum[r4] += __shfl_xor(csum[r4], mask);
        if ((l & 15) == 0) {
            float cb2v = cb2[0];
            #pragma unroll
            for (int r4 = 0; r4 < 4; r4++) {
                int row = row0 + (l >> 4)*4 + r4;
                float cacc = csum[r4] + cb2v;
                int d = s_dst[row];
                atomicAdd(&cdelta[d*3+0], cacc * s_rel[row*3+0]);
                atomicAdd(&cdelta[d*3+1], cacc * s_rel[row*3+1]);
                atomicAdd(&cdelta[d*3+2], cacc * s_rel[row*3+2]);
            }
        }
    }
}

// ---------------- node kernel: feats_out = feats + MLP([feats, m_i]) --------
__global__ __launch_bounds__(256)
void node_kernel(const float* __restrict__ feats, const float* __restrict__ m_i,
                 const float* __restrict__ nw1, const float* __restrict__ nb1,
                 const float* __restrict__ nw2, const float* __restrict__ nb2,
                 float* __restrict__ fout)
{
    __shared__ float s_w1t[NH * NIN];
    __shared__ float s_b1[NH];
    __shared__ float s_w2[NH * EMB];
    __shared__ float s_b2[EMB];
    const int tid = threadIdx.x;
    for (int idx = tid; idx < NH * NIN; idx += 256) {
        int k = idx / NIN, i = idx - k * NIN;
        s_w1t[idx] = nw1[i * NH + k];
    }
    for (int idx = tid; idx < NH * EMB; idx += 256) s_w2[idx] = nw2[idx];
    if (tid < NH) s_b1[tid] = nb1[tid];
    if (tid < EMB) s_b2[tid] = nb2[tid];
    __syncthreads();

    int n = blockIdx.x * 256 + tid;
    if (n >= N_NODES) return;

    float in[NIN];
    const float4* fp = reinterpret_cast<const float4*>(feats + (size_t)n * EMB);
    #pragma unroll
    for (int q = 0; q < 6; q++) {
        float4 v = fp[q];
        in[q*4] = v.x; in[q*4+1] = v.y; in[q*4+2] = v.z; in[q*4+3] = v.w;
    }
    const float4* mp = reinterpret_cast<const float4*>(m_i + (size_t)n * MDIM);
    #pragma unroll
    for (int q = 0; q < 16; q++) {
        float4 v = mp[q];
        in[EMB+q*4] = v.x; in[EMB+q*4+1] = v.y; in[EMB+q*4+2] = v.z; in[EMB+q*4+3] = v.w;
    }
    float o[EMB];
    #pragma unroll
    for (int j = 0; j < EMB; j++) o[j] = in[j] + s_b2[j];
    for (int k = 0; k < NH; k++) {
        const float* w1 = &s_w1t[k * NIN];
        float a0 = 0.f, a1 = 0.f, a2 = 0.f, a3 = 0.f;
        #pragma unroll
        for (int i = 0; i < NIN; i += 4) {
            a0 = fmaf(in[i],   w1[i],   a0);
            a1 = fmaf(in[i+1], w1[i+1], a1);
            a2 = fmaf(in[i+2], w1[i+2], a2);
            a3 = fmaf(in[i+3], w1[i+3], a3);
        }
        float h = siluf(s_b1[k] + ((a0 + a1) + (a2 + a3)));
        const float* w2 = &s_w2[k * EMB];
        #pragma unroll
        for (int j = 0; j < EMB; j++) o[j] = fmaf(h, w2[j], o[j]);
    }
    float4* dst = reinterpret_cast<float4*>(fout + (size_t)n * EMB);
    #pragma unroll
    for (int q = 0; q < 6; q++) dst[q] = make_float4(o[q*4], o[q*4+1], o[q*4+2], o[q*4+3]);
}

// ---------------- coors update ----------------------------------------------
__global__ void coor_kernel(const float* __restrict__ pos, const float* __restrict__ cdelta,
                            float* __restrict__ out)
{
    int i = blockIdx.x * blockDim.x + threadIdx.x;
    if (i < N_NODES * 3) out[i] = pos[i] + cdelta[i];
}

// ---------------- fused MFMA FFNN: 3 layers + pooling, 64 nodes/block -------
// sH [64][256] bf16 (32KB) reused by all phases; x lives in first 16KB as
// [64][128] and is prefetched to regs before L0 overwrites it.
__global__ __launch_bounds__(256, 4)
void ffnn_fused(const float* __restrict__ f0, const float* __restrict__ f1,
                const float* __restrict__ f2,
                const bf16_t* __restrict__ W0p, const bf16_t* __restrict__ W1p,
                const bf16_t* __restrict__ W2p,
                const float* __restrict__ b0, const float* __restrict__ b1,
                const float* __restrict__ b2,
                const int* __restrict__ batch, float* __restrict__ pooled)
{
    __shared__ __align__(16) bf16_t sH[NTILE * 256]; // 32KB
    __shared__ int s_batch[NTILE];
    const int t = threadIdx.x;
    const int w = t >> 6, l = t & 63;
    const int row0 = w * 16;
    const int n0 = blockIdx.x * NTILE;

    // ---- gather x = silu(concat(f0,f1,f2)) -> sH-as-[64][128] bf16 swz ----
    {
        int row = t >> 2, part = t & 3;
        int n = n0 + row;
        bool valid = n < N_NODES;
        if (part == 3) s_batch[row] = valid ? batch[n] : -1;
        #pragma unroll
        for (int gi = 0; gi < 4; gi++) {
            int g = part * 4 + gi;
            bf16x8 pk;
            #pragma unroll
            for (int j = 0; j < 8; j++) pk[j] = (bf16_t)0.f;
            if (valid && g < 9) {
                const float* sp = (g < 3) ? f0 + (size_t)n*EMB + 8*g
                                : (g < 6) ? f1 + (size_t)n*EMB + 8*(g-3)
                                          : f2 + (size_t)n*EMB + 8*(g-6);
                float4 a = ((const float4*)sp)[0], b = ((const float4*)sp)[1];
                pk[0]=(bf16_t)siluf(a.x); pk[1]=(bf16_t)siluf(a.y);
                pk[2]=(bf16_t)siluf(a.z); pk[3]=(bf16_t)siluf(a.w);
                pk[4]=(bf16_t)siluf(b.x); pk[5]=(bf16_t)siluf(b.y);
                pk[6]=(bf16_t)siluf(b.z); pk[7]=(bf16_t)siluf(b.w);
            }
            *(bf16x8*)&sH[row*128 + (g ^ (row & 7))*8] = pk;
        }
    }
    __syncthreads();

    // ---- L0: prefetch A to regs, then h = silu(x @ W0p + b0) ----
    bf16x8 a0[4];
    {
        int r = row0 + (l & 15);
        #pragma unroll
        for (int ks = 0; ks < 4; ks++)
            a0[ks] = *(const bf16x8*)&sH[r*128 + ((ks*4 + (l >> 4)) ^ (r & 7))*8];
    }
    __syncthreads();   // all x reads done before sH is overwritten

    f32x4 acc[16];
    #pragma unroll
    for (int nt = 0; nt < 16; nt++) {
        float bv = b0[nt*16 + (l & 15)];
        acc[nt] = (f32x4){bv, bv, bv, bv};
    }
    #pragma unroll
    for (int ks = 0; ks < 4; ks++)
        #pragma unroll
        for (int nt = 0; nt < 16; nt++) {
            int n = nt*16 + (l & 15);
            bf16x8 b = *(const bf16x8*)&W0p[n*128 + (ks*4 + (l >> 4))*8];
            acc[nt] = __builtin_amdgcn_mfma_f32_16x16x32_bf16(a0[ks], b, acc[nt], 0, 0, 0);
        }
    #pragma unroll
    for (int nt = 0; nt < 16; nt++)
        #pragma unroll
        for (int r4 = 0; r4 < 4; r4++) {
            int row = row0 + (l >> 4)*4 + r4;
            int col = nt*16 + (l & 15);
            sH[row*256 + ((col >> 3) ^ (row & 7))*8 + (col & 7)] = (bf16_t)siluf(acc[nt][r4]);
        }
    __syncthreads();

    // ---- L1 and L2: h = silu(h @ Wp + b) ----
    #pragma unroll
    for (int layer = 0; layer < 2; layer++) {
        const bf16_t* Wp = layer ? W2p : W1p;
        const float*  bb = layer ? b2  : b1;
        #pragma unroll
        for (int nt = 0; nt < 16; nt++) {
            float bv = bb[nt*16 + (l & 15)];
            acc[nt] = (f32x4){bv, bv, bv, bv};
        }
        for (int ks = 0; ks < 8; ks++) {
            int r = row0 + (l & 15);
            bf16x8 a = *(const bf16x8*)&sH[r*256 + ((ks*4 + (l >> 4)) ^ (r & 7))*8];
            #pragma unroll
            for (int nt = 0; nt < 16; nt++) {
                int n = nt*16 + (l & 15);
                bf16x8 b = *(const bf16x8*)&Wp[n*256 + (ks*4 + (l >> 4))*8];
                acc[nt] = __builtin_amdgcn_mfma_f32_16x16x32_bf16(a, b, acc[nt], 0, 0, 0);
            }
        }
        __syncthreads();   // all h reads done before overwrite
        #pragma unroll
        for (int nt = 0; nt < 16; nt++)
            #pragma unroll
            for (int r4 = 0; r4 < 4; r4++) {
                int row = row0 + (l >> 4)*4 + r4;
                int col = nt*16 + (l & 15);
                sH[row*256 + ((col >> 3) ^ (row & 7))*8 + (col & 7)] = (bf16_t)siluf(acc[nt][r4]);
            }
        __syncthreads();
    }

    // ---- fused pooling: batch-run reduction over rows, one col per thread --
    {
        int j = t;
        int g = j >> 3, jo = j & 7;
        int cur = -1;
        float run = 0.f;
        for (int i = 0; i < NTILE; i++) {
            int bb = s_batch[i];
            if (bb != cur) {
                if (cur >= 0) atomicAdd(&pooled[cur * MLP + j], run);
                run = 0.f; cur = bb;
            }
            if (bb >= 0) run += (float)sH[i*256 + (g ^ (i & 7))*8 + jo];
        }
        if (cur >= 0) atomicAdd(&pooled[cur * MLP + j], run);
    }
}

// ---------------- final: sigmoid((pooled/cnt) @ fow + fob) ------------------
__global__ void final_kernel(const float* __restrict__ pooled, const float* __restrict__ cnt,
                             const float* __restrict__ fow, const float* __restrict__ fob,
                             float* __restrict__ out)
{
    int t = threadIdx.x;  // 256 = 64 graphs * 4 outputs
    int bg = t >> 2, o = t & 3;
    float c = fmaxf(cnt[bg], 1.0f);
    float acc = 0.f;
    for (int i = 0; i < MLP; i++) acc = fmaf(pooled[bg * MLP + i], fow[i * 4 + o], acc);
    acc = acc / c + fob[o];
    out[t] = 1.0f / (1.0f + __expf(-acc));
}

extern "C" void kernel_launch(void* const* d_in, const int* in_sizes, int n_in,
                              void* d_out, int out_size, void* d_ws, size_t ws_size,
                              hipStream_t stream)
{
    const int*   z     = (const int*)  d_in[0];
    const float* pos   = (const float*)d_in[1];
    const int*   eidx  = (const int*)  d_in[2];
    const int*   batch = (const int*)  d_in[3];
    const float* embt  = (const float*)d_in[4];
    const float* embw  = (const float*)d_in[5];
    const float* embb  = (const float*)d_in[6];
    const float* ew1   = (const float*)d_in[7];
    const float* eb1   = (const float*)d_in[8];
    const float* ew2   = (const float*)d_in[9];
    const float* eb2   = (const float*)d_in[10];
    const float* cw1   = (const float*)d_in[11];
    const float* cb1   = (const float*)d_in[12];
    const float* cw2   = (const float*)d_in[13];
    const float* cb2   = (const float*)d_in[14];
    const float* nw1   = (const float*)d_in[15];
    const float* nb1   = (const float*)d_in[16];
    const float* nw2   = (const float*)d_in[17];
    const float* nb2   = (const float*)d_in[18];
    const float* f0w   = (const float*)d_in[19];
    const float* f0b   = (const float*)d_in[20];
    const float* f1w   = (const float*)d_in[21];
    const float* f1b   = (const float*)d_in[22];
    const float* f2w   = (const float*)d_in[23];
    const float* f2b   = (const float*)d_in[24];
    const float* fow   = (const float*)d_in[25];
    const float* fob   = (const float*)d_in[26];

    float* ws     = (float*)d_ws;
    float* f0     = ws;
    float* f1v    = f0 + (size_t)N_NODES * EMB;
    float* f2v    = f1v + (size_t)N_NODES * EMB;
    float* coorsA = f2v + (size_t)N_NODES * EMB;
    float* cdelta = coorsA + N_NODES * 3;
    float* m_i    = cdelta + N_NODES * 3;
    float* pooled = m_i + (size_t)N_NODES * MDIM;
    float* cnt    = pooled + N_GRAPHS * MLP;
    int*   deg    = (int*)(cnt + N_GRAPHS);
    int*   cursor = deg + N_NODES;
    int*   srcs_s = cursor + N_NODES;
    int*   dsts_s = srcs_s + N_EDGES;
    bf16_t* packw = (bf16_t*)(dsts_s + N_EDGES);
    bf16_t* W1t0  = packw;
    bf16_t* W1t1  = W1t0 + PK_W1;
    bf16_t* W2t0  = W1t1 + PK_W1;
    bf16_t* W2t1  = W2t0 + PK_W2;
    bf16_t* CW1t  = W2t1 + PK_W2;
    bf16_t* W0p   = CW1t + PK_CW;
    bf16_t* W1p   = W0p + PK_F0;
    bf16_t* W2p   = W1p + PK_FM;

    hipMemsetAsync(cdelta, 0, N_NODES * 3 * sizeof(float), stream);
    hipMemsetAsync(m_i, 0, (size_t)N_NODES * MDIM * sizeof(float), stream);
    hipMemsetAsync(pooled, 0, (N_GRAPHS * MLP + N_GRAPHS) * sizeof(float), stream);
    hipMemsetAsync(deg, 0, N_NODES * sizeof(int), stream);

    const int* e_src = eidx;
    const int* e_dst = eidx + N_EDGES;
    pack_kernel<<<(PK_TOT + 255) / 256, 256, 0, stream>>>(ew1, eb1, ew2, eb2, cw1,
                                                          f0w, f1w, f2w, packw);
    hist_kernel<<<(N_EDGES + 255) / 256, 256, 0, stream>>>(e_dst, deg);
    scan_kernel<<<1, 1024, 0, stream>>>(deg, cursor);
    scatter_kernel<<<(N_EDGES + 255) / 256, 256, 0, stream>>>(e_src, e_dst, cursor, srcs_s, dsts_s);

    embed_kernel<<<(N_NODES + 255) / 256, 256, 0, stream>>>(z, embt, embw, embb, batch, f0, cnt);

    const int EBLK = N_EDGES / ETILE; // 12500
    edge_mfma<1><<<EBLK, 256, 0, stream>>>(f0, pos, srcs_s, dsts_s,
        W1t0, W2t0, CW1t, cb1, cw2, cb2, m_i, cdelta);
    node_kernel<<<(N_NODES + 255) / 256, 256, 0, stream>>>(f0, m_i, nw1, nb1, nw2, nb2, f1v);
    coor_kernel<<<(N_NODES * 3 + 255) / 256, 256, 0, stream>>>(pos, cdelta, coorsA);
    hipMemsetAsync(m_i, 0, (size_t)N_NODES * MDIM * sizeof(float), stream);
    edge_mfma<0><<<EBLK, 256, 0, stream>>>(f1v, coorsA, srcs_s, dsts_s,
        W1t1, W2t1, CW1t, cb1, cw2, cb2, m_i, nullptr);
    node_kernel<<<(N_NODES + 255) / 256, 256, 0, stream>>>(f1v, m_i,
        nw1 + NIN * NH, nb1 + NH, nw2 + NH * EMB, nb2 + EMB, f2v);

    const int FBLK = (N_NODES + NTILE - 1) / NTILE; // 782
    ffnn_fused<<<FBLK, 256, 0, stream>>>(f0, f1v, f2v, W0p, W1p, W2p,
                                         f0b, f1b, f2b, batch, pooled);

    final_kernel<<<1, 256, 0, stream>>>(pooled, cnt, fow, fob, (float*)d_out);
}

// Round 4
// 1104.762 us; speedup vs baseline: 6.2898x; 1.2152x over previous
//
#include <hip/hip_runtime.h>
#include <hip/hip_bf16.h>

#define N_NODES  50000
#define N_EDGES  800000
#define N_GRAPHS 64
#define EMB      24
#define MDIM     64
#define EDGE_IN  57
#define EH       114   // EDGE_IN*2
#define CH       256   // M_DIM*4
#define NIN      88    // EMB+MDIM
#define NH       48    // EMB*2
#define MLP      256
#define ETILE    128
#define NTILE    64

typedef __bf16 bf16_t;
typedef __bf16 bf16x8 __attribute__((ext_vector_type(8)));
typedef __bf16 bf16x4 __attribute__((ext_vector_type(4)));
typedef float  f32x4  __attribute__((ext_vector_type(4)));

__device__ __forceinline__ float siluf(float x) {
    return x * __builtin_amdgcn_rcpf(1.0f + __expf(-x));
}

// ---------------- embedding: feats0 = emb_table[z] @ emb_w + emb_b ----------
__global__ void embed_kernel(const int* __restrict__ z, const float* __restrict__ table,
                             const float* __restrict__ w, const float* __restrict__ b,
                             const int* __restrict__ batch, float* __restrict__ f0,
                             bf16_t* __restrict__ fb0, float* __restrict__ cnt)
{
    int n = blockIdx.x * blockDim.x + threadIdx.x;
    if (n >= N_NODES) return;
    float r[EMB];
    const float4* tr = reinterpret_cast<const float4*>(table + z[n] * EMB);
    #pragma unroll
    for (int q = 0; q < 6; q++) {
        float4 v = tr[q];
        r[q*4] = v.x; r[q*4+1] = v.y; r[q*4+2] = v.z; r[q*4+3] = v.w;
    }
    float o[EMB];
    #pragma unroll
    for (int j = 0; j < EMB; j++) o[j] = b[j];
    #pragma unroll
    for (int i = 0; i < EMB; i++) {
        #pragma unroll
        for (int j = 0; j < EMB; j++) o[j] = fmaf(r[i], w[i*EMB + j], o[j]);
    }
    float4* dst = reinterpret_cast<float4*>(f0 + (size_t)n * EMB);
    #pragma unroll
    for (int q = 0; q < 6; q++) dst[q] = make_float4(o[q*4], o[q*4+1], o[q*4+2], o[q*4+3]);
    bf16x8* bdst = reinterpret_cast<bf16x8*>(fb0 + (size_t)n * EMB);
    #pragma unroll
    for (int q = 0; q < 3; q++) {
        bf16x8 pk;
        #pragma unroll
        for (int j = 0; j < 8; j++) pk[j] = (bf16_t)o[q*8 + j];
        bdst[q] = pk;
    }
    atomicAdd(&cnt[batch[n]], 1.0f);
}

// ---------------- weight pre-pack to bf16 MFMA layout (A-operand [n][k]) ----
#define PK_W1   (128*64)
#define PK_W2   (64*128)
#define PK_CW   (256*64)
#define PK_F0   (256*128)
#define PK_FM   (256*256)
#define PK_TOT  (2*PK_W1 + 2*PK_W2 + PK_CW + PK_F0 + 2*PK_FM)
__global__ void pack_kernel(const float* __restrict__ ew1, const float* __restrict__ eb1,
                            const float* __restrict__ ew2, const float* __restrict__ eb2,
                            const float* __restrict__ cw1, const float* __restrict__ f0w,
                            const float* __restrict__ f1w, const float* __restrict__ f2w,
                            bf16_t* __restrict__ pw)
{
    int idx = blockIdx.x * blockDim.x + threadIdx.x;
    if (idx >= PK_TOT) return;
    float v = 0.0f;
    if (idx < 2 * PK_W1) {
        int l = idx / PK_W1, r = idx - l * PK_W1;
        int n = r >> 6, k = r & 63;
        if (n < EH && k < EDGE_IN)       v = ew1[(l * EDGE_IN + k) * EH + n];
        else if (n < EH && k == EDGE_IN) v = eb1[l * EH + n];
    } else if (idx < 2 * PK_W1 + 2 * PK_W2) {
        int r0 = idx - 2 * PK_W1;
        int l = r0 / PK_W2, r = r0 - l * PK_W2;
        int n = r >> 7, k = r & 127;
        if (k < EH)       v = ew2[(l * EH + k) * MDIM + n];
        else if (k == EH) v = eb2[l * MDIM + n];
    } else if (idx < 2 * PK_W1 + 2 * PK_W2 + PK_CW) {
        int r = idx - (2 * PK_W1 + 2 * PK_W2);
        int n = r >> 6, k = r & 63;
        v = cw1[k * CH + n];
    } else if (idx < 2 * PK_W1 + 2 * PK_W2 + PK_CW + PK_F0) {
        int r = idx - (2 * PK_W1 + 2 * PK_W2 + PK_CW);
        int n = r >> 7, k = r & 127;
        if (k < 72) v = f0w[k * MLP + n];
    } else {
        int r0 = idx - (2 * PK_W1 + 2 * PK_W2 + PK_CW + PK_F0);
        int l = r0 / PK_FM, r = r0 - l * PK_FM;
        int n = r >> 8, k = r & 255;
        v = (l == 0) ? f1w[k * MLP + n] : f2w[k * MLP + n];
    }
    pw[idx] = (bf16_t)v;
}

// ---------------- CSR build --------------------------------------------------
__global__ void hist_kernel(const int* __restrict__ dst, int* __restrict__ deg)
{
    int e = blockIdx.x * blockDim.x + threadIdx.x;
    if (e < N_EDGES) atomicAdd(&deg[dst[e]], 1);
}

__global__ __launch_bounds__(1024)
void scan_kernel(const int* __restrict__ deg, int* __restrict__ cursor)
{
    __shared__ int part[1024];
    int t = threadIdx.x;
    const int PER = 49;
    int base = t * PER;
    int s = 0;
    for (int i = 0; i < PER; i++) {
        int p = base + i;
        if (p < N_NODES) s += deg[p];
    }
    part[t] = s;
    __syncthreads();
    for (int off = 1; off < 1024; off <<= 1) {
        int add = (t >= off) ? part[t - off] : 0;
        __syncthreads();
        part[t] += add;
        __syncthreads();
    }
    int run = (t > 0) ? part[t - 1] : 0;
    for (int i = 0; i < PER; i++) {
        int p = base + i;
        if (p < N_NODES) { cursor[p] = run; run += deg[p]; }
    }
}

__global__ void scatter_kernel(const int* __restrict__ src, const int* __restrict__ dst,
                               int* __restrict__ cursor, int* __restrict__ srcs_s,
                               int* __restrict__ dsts_s)
{
    int e = blockIdx.x * blockDim.x + threadIdx.x;
    if (e >= N_EDGES) return;
    int d = dst[e];
    int pos = atomicAdd(&cursor[d], 1);
    srcs_s[pos] = src[e];
    dsts_s[pos] = d;
}

// ---------------- fused MFMA edge kernel (transposed GEMMs) -----------------
// 256 thr / 4 waves, 128 edges. A-operand = weights [n][k] (global),
// B-operand = data^T (LDS, contiguous bf16x8 per lane). D = out^T: lane holds
// 4 consecutive FEATURES of ONE edge -> b64/b128 epilogue stores.
// LDS union R1raw (32KB): Ein bf16 [128][64] -> H1 bf16 [128][128] ->
// M f32 [128][64]. Swizzle: 16B granule g at row e -> g ^ (e&7).
template<int COOR>
__global__ __launch_bounds__(256, 4)
void edge_mfma(const bf16_t* __restrict__ fb, const float* __restrict__ coors,
               const int* __restrict__ srcs_s, const int* __restrict__ dsts_s,
               const bf16_t* __restrict__ W1t, const bf16_t* __restrict__ W2t,
               const bf16_t* __restrict__ CW1t, const float* __restrict__ cb1,
               const float* __restrict__ cw2, const float* __restrict__ cb2,
               float* __restrict__ m_i, float* __restrict__ cdelta)
{
    __shared__ __align__(16) char R1raw[ETILE * 64 * 4]; // 32KB
    __shared__ float s_rel[COOR ? ETILE * 3 : 4];
    __shared__ int   s_dst[ETILE];
    bf16_t* R1 = (bf16_t*)R1raw;
    float*  Mf32 = (float*)R1raw;

    const int t = threadIdx.x;
    const int w = t >> 6;
    const int l = t & 63;
    const int row0 = w * 32;          // wave's 32-edge stripe
    const int ebase = blockIdx.x * ETILE;
    const int l15 = l & 15, l4 = l >> 4;

    // ---- gather: 2 threads per edge, bf16 feats ----
    {
        int e_loc = t >> 1, half = t & 1;
        int e = ebase + e_loc;
        int s = srcs_s[e], d = dsts_s[e];
        if (half == 0) {
            s_dst[e_loc] = d;
            const bf16x8* fp = reinterpret_cast<const bf16x8*>(fb + (size_t)d * EMB);
            #pragma unroll
            for (int g = 0; g < 3; g++)
                *(bf16x8*)&R1[e_loc*64 + (g ^ (e_loc & 7))*8] = fp[g];
        } else {
            const bf16x8* fp = reinterpret_cast<const bf16x8*>(fb + (size_t)s * EMB);
            #pragma unroll
            for (int g = 0; g < 3; g++)
                *(bf16x8*)&R1[e_loc*64 + ((g + 3) ^ (e_loc & 7))*8] = fp[g];
            float rx = coors[s*3+0] - coors[d*3+0];
            float ry = coors[s*3+1] - coors[d*3+1];
            float rz = coors[s*3+2] - coors[d*3+2];
            float d2 = rx*rx + ry*ry + rz*rz;
            if (COOR) { s_rel[e_loc*3+0] = rx; s_rel[e_loc*3+1] = ry; s_rel[e_loc*3+2] = rz; }
            bf16x8 p6, p7;
            p6[0]=(bf16_t)__sinf(d2);        p6[1]=(bf16_t)__sinf(d2*0.5f);
            p6[2]=(bf16_t)__sinf(d2*0.25f);  p6[3]=(bf16_t)__sinf(d2*0.125f);
            p6[4]=(bf16_t)__cosf(d2);        p6[5]=(bf16_t)__cosf(d2*0.5f);
            p6[6]=(bf16_t)__cosf(d2*0.25f);  p6[7]=(bf16_t)__cosf(d2*0.125f);
            p7[0]=(bf16_t)d2; p7[1]=(bf16_t)1.0f;
            p7[2]=(bf16_t)0.f; p7[3]=(bf16_t)0.f; p7[4]=(bf16_t)0.f;
            p7[5]=(bf16_t)0.f; p7[6]=(bf16_t)0.f; p7[7]=(bf16_t)0.f;
            *(bf16x8*)&R1[e_loc*64 + (6 ^ (e_loc & 7))*8] = p6;
            *(bf16x8*)&R1[e_loc*64 + (7 ^ (e_loc & 7))*8] = p7;
        }
    }
    __syncthreads();

    // ---- GEMM1: H1^T[f][e] = W1t[f][k] * Ein^T[k][e] ----
    f32x4 acc1[2][8];
    #pragma unroll
    for (int et = 0; et < 2; et++)
        #pragma unroll
        for (int ft = 0; ft < 8; ft++) acc1[et][ft] = (f32x4){0.f,0.f,0.f,0.f};
    #pragma unroll
    for (int ks = 0; ks < 2; ks++) {
        bf16x8 bfrag[2];
        #pragma unroll
        for (int et = 0; et < 2; et++) {
            int e = row0 + et*16 + l15;
            bfrag[et] = *(const bf16x8*)&R1[e*64 + ((ks*4 + l4) ^ (e & 7))*8];
        }
        #pragma unroll
        for (int ft = 0; ft < 8; ft++) {
            bf16x8 a = *(const bf16x8*)&W1t[(ft*16 + l15)*64 + (ks*4 + l4)*8];
            acc1[0][ft] = __builtin_amdgcn_mfma_f32_16x16x32_bf16(a, bfrag[0], acc1[0][ft], 0, 0, 0);
            acc1[1][ft] = __builtin_amdgcn_mfma_f32_16x16x32_bf16(a, bfrag[1], acc1[1][ft], 0, 0, 0);
        }
    }
    __syncthreads();
    // write H1[e][f] = silu; f==114 -> 1.0 (GEMM2 bias slot); b64 stores
    #pragma unroll
    for (int et = 0; et < 2; et++)
        #pragma unroll
        for (int ft = 0; ft < 8; ft++) {
            int e = row0 + et*16 + l15;
            int f0 = ft*16 + l4*4;
            bf16x4 pk;
            #pragma unroll
            for (int r4 = 0; r4 < 4; r4++) {
                float hv = siluf(acc1[et][ft][r4]);
                if (f0 + r4 == EH) hv = 1.0f;
                pk[r4] = (bf16_t)hv;
            }
            *(bf16x4*)&R1[e*128 + ((f0 >> 3) ^ (e & 7))*8 + (f0 & 7)] = pk;
        }
    __syncthreads();

    // ---- GEMM2: M^T[f][e] = W2t[f][k] * H1^T[k][e] ----
    f32x4 acc2[2][4];
    #pragma unroll
    for (int et = 0; et < 2; et++)
        #pragma unroll
        for (int ft = 0; ft < 4; ft++) acc2[et][ft] = (f32x4){0.f,0.f,0.f,0.f};
    #pragma unroll
    for (int ks = 0; ks < 4; ks++) {
        bf16x8 bfrag[2];
        #pragma unroll
        for (int et = 0; et < 2; et++) {
            int e = row0 + et*16 + l15;
            bfrag[et] = *(const bf16x8*)&R1[e*128 + ((ks*4 + l4) ^ (e & 7))*8];
        }
        #pragma unroll
        for (int ft = 0; ft < 4; ft++) {
            bf16x8 a = *(const bf16x8*)&W2t[(ft*16 + l15)*128 + (ks*4 + l4)*8];
            acc2[0][ft] = __builtin_amdgcn_mfma_f32_16x16x32_bf16(a, bfrag[0], acc2[0][ft], 0, 0, 0);
            acc2[1][ft] = __builtin_amdgcn_mfma_f32_16x16x32_bf16(a, bfrag[1], acc2[1][ft], 0, 0, 0);
        }
    }
    __syncthreads();
    // write M[e][f] f32 (swizzled 16B granules), b128 stores
    #pragma unroll
    for (int et = 0; et < 2; et++)
        #pragma unroll
        for (int ft = 0; ft < 4; ft++) {
            int e = row0 + et*16 + l15;
            int f0 = ft*16 + l4*4;
            f32x4 v;
            #pragma unroll
            for (int r4 = 0; r4 < 4; r4++) v[r4] = siluf(acc2[et][ft][r4]);
            *(f32x4*)&Mf32[e*64 + (((f0 >> 2) ^ (e & 7)) << 2)] = v;
        }
    __syncthreads();

    // ---- m_i run-reduction (dst-sorted; 32-edge groups per wave) ----
    {
        int col = t & 63;
        int gsw_base = col >> 2, cw = col & 3;
        int gb = w * 32;
        int cur = s_dst[gb];
        float run = 0.f;
        for (int i = 0; i < 32; i++) {
            int row = gb + i;
            int d = s_dst[row];
            float v = Mf32[row*64 + ((gsw_base ^ (row & 7)) << 2) + cw];
            if (d != cur) { atomicAdd(&m_i[(size_t)cur*64 + col], run); run = 0.f; cur = d; }
            run += v;
        }
        atomicAdd(&m_i[(size_t)cur*64 + col], run);
    }

    // ---- GEMM3 + coor scatter (layer 0 only) ----
    if (COOR) {
        float csum[2] = {0.f, 0.f};
        #pragma unroll
        for (int half = 0; half < 2; half++) {
            f32x4 acc3[2][8];
            #pragma unroll
            for (int et = 0; et < 2; et++)
                #pragma unroll
                for (int ft = 0; ft < 8; ft++) acc3[et][ft] = (f32x4){0.f,0.f,0.f,0.f};
            #pragma unroll
            for (int ks = 0; ks < 2; ks++) {
                bf16x8 bfrag[2];
                #pragma unroll
                for (int et = 0; et < 2; et++) {
                    int e = row0 + et*16 + l15;
                    int g0 = (ks*4 + l4) * 2;   // f32 16B-granule index (even)
                    f32x4 lo = *(const f32x4*)&Mf32[e*64 + ((g0 ^ (e & 7)) << 2)];
                    f32x4 hi = *(const f32x4*)&Mf32[e*64 + (((g0 + 1) ^ (e & 7)) << 2)];
                    bf16x8 bk;
                    #pragma unroll
                    for (int j = 0; j < 4; j++) { bk[j] = (bf16_t)lo[j]; bk[j+4] = (bf16_t)hi[j]; }
                    bfrag[et] = bk;
                }
                #pragma unroll
                for (int ft = 0; ft < 8; ft++) {
                    bf16x8 a = *(const bf16x8*)&CW1t[(half*128 + ft*16 + l15)*64 + (ks*4 + l4)*8];
                    acc3[0][ft] = __builtin_amdgcn_mfma_f32_16x16x32_bf16(a, bfrag[0], acc3[0][ft], 0, 0, 0);
                    acc3[1][ft] = __builtin_amdgcn_mfma_f32_16x16x32_bf16(a, bfrag[1], acc3[1][ft], 0, 0, 0);
                }
            }
            #pragma unroll
            for (int ft = 0; ft < 8; ft++) {
                int f0 = half*128 + ft*16 + l4*4;
                float4 c1 = *(const float4*)&cb1[f0];
                float4 w2 = *(const float4*)&cw2[f0];
                #pragma unroll
                for (int et = 0; et < 2; et++) {
                    csum[et] = fmaf(siluf(acc3[et][ft][0] + c1.x), w2.x, csum[et]);
                    csum[et] = fmaf(siluf(acc3[et][ft][1] + c1.y), w2.y, csum[et]);
                    csum[et] = fmaf(siluf(acc3[et][ft][2] + c1.z), w2.z, csum[et]);
                    csum[et] = fmaf(siluf(acc3[et][ft][3] + c1.w), w2.w, csum[et]);
                }
            }
        }
        #pragma unroll
        for (int et = 0; et < 2; et++) {
            csum[et] += __shfl_xor(csum[et], 16);
            csum[et] += __shfl_xor(csum[et], 32);
        }
        if (l < 16) {
            float cb2v = cb2[0];
            #pragma unroll
            for (int et = 0; et < 2; et++) {
                int row = row0 + et*16 + l;
                float cacc = csum[et] + cb2v;
                int d = s_dst[row];
                atomicAdd(&cdelta[d*3+0], cacc * s_rel[row*3+0]);
                atomicAdd(&cdelta[d*3+1], cacc * s_rel[row*3+1]);
                atomicAdd(&cdelta[d*3+2], cacc * s_rel[row*3+2]);
            }
        }
    }
}

// ---------------- node kernel: feats_out = feats + MLP([feats, m_i]) --------
template<int EMIT_BF16>
__global__ __launch_bounds__(256)
void node_kernel(const float* __restrict__ feats, const float* __restrict__ m_i,
                 const float* __restrict__ nw1, const float* __restrict__ nb1,
                 const float* __restrict__ nw2, const float* __restrict__ nb2,
                 float* __restrict__ fout, bf16_t* __restrict__ fbout)
{
    __shared__ float s_w1t[NH * NIN];
    __shared__ float s_b1[NH];
    __shared__ float s_w2[NH * EMB];
    __shared__ float s_b2[EMB];
    const int tid = threadIdx.x;
    for (int idx = tid; idx < NH * NIN; idx += 256) {
        int k = idx / NIN, i = idx - k * NIN;
        s_w1t[idx] = nw1[i * NH + k];
    }
    for (int idx = tid; idx < NH * EMB; idx += 256) s_w2[idx] = nw2[idx];
    if (tid < NH) s_b1[tid] = nb1[tid];
    if (tid < EMB) s_b2[tid] = nb2[tid];
    __syncthreads();

    int n = blockIdx.x * 256 + tid;
    if (n >= N_NODES) return;

    float in[NIN];
    const float4* fp = reinterpret_cast<const float4*>(feats + (size_t)n * EMB);
    #pragma unroll
    for (int q = 0; q < 6; q++) {
        float4 v = fp[q];
        in[q*4] = v.x; in[q*4+1] = v.y; in[q*4+2] = v.z; in[q*4+3] = v.w;
    }
    const float4* mp = reinterpret_cast<const float4*>(m_i + (size_t)n * MDIM);
    #pragma unroll
    for (int q = 0; q < 16; q++) {
        float4 v = mp[q];
        in[EMB+q*4] = v.x; in[EMB+q*4+1] = v.y; in[EMB+q*4+2] = v.z; in[EMB+q*4+3] = v.w;
    }
    float o[EMB];
    #pragma unroll
    for (int j = 0; j < EMB; j++) o[j] = in[j] + s_b2[j];
    for (int k = 0; k < NH; k++) {
        const float* w1 = &s_w1t[k * NIN];
        float a0 = 0.f, a1 = 0.f, a2 = 0.f, a3 = 0.f;
        #pragma unroll
        for (int i = 0; i < NIN; i += 4) {
            a0 = fmaf(in[i],   w1[i],   a0);
            a1 = fmaf(in[i+1], w1[i+1], a1);
            a2 = fmaf(in[i+2], w1[i+2], a2);
            a3 = fmaf(in[i+3], w1[i+3], a3);
        }
        float h = siluf(s_b1[k] + ((a0 + a1) + (a2 + a3)));
        const float* w2 = &s_w2[k * EMB];
        #pragma unroll
        for (int j = 0; j < EMB; j++) o[j] = fmaf(h, w2[j], o[j]);
    }
    float4* dst = reinterpret_cast<float4*>(fout + (size_t)n * EMB);
    #pragma unroll
    for (int q = 0; q < 6; q++) dst[q] = make_float4(o[q*4], o[q*4+1], o[q*4+2], o[q*4+3]);
    if (EMIT_BF16) {
        bf16x8* bdst = reinterpret_cast<bf16x8*>(fbout + (size_t)n * EMB);
        #pragma unroll
        for (int q = 0; q < 3; q++) {
            bf16x8 pk;
            #pragma unroll
            for (int j = 0; j < 8; j++) pk[j] = (bf16_t)o[q*8 + j];
            bdst[q] = pk;
        }
    }
}

// ---------------- coors update ----------------------------------------------
__global__ void coor_kernel(const float* __restrict__ pos, const float* __restrict__ cdelta,
                            float* __restrict__ out)
{
    int i = blockIdx.x * blockDim.x + threadIdx.x;
    if (i < N_NODES * 3) out[i] = pos[i] + cdelta[i];
}

// ---------------- fused MFMA FFNN: 3 layers + pooling, 64 nodes/block -------
__global__ __launch_bounds__(256, 4)
void ffnn_fused(const float* __restrict__ f0, const float* __restrict__ f1,
                const float* __restrict__ f2,
                const bf16_t* __restrict__ W0p, const bf16_t* __restrict__ W1p,
                const bf16_t* __restrict__ W2p,
                const float* __restrict__ b0, const float* __restrict__ b1,
                const float* __restrict__ b2,
                const int* __restrict__ batch, float* __restrict__ pooled)
{
    __shared__ __align__(16) bf16_t sH[NTILE * 256]; // 32KB
    __shared__ int s_batch[NTILE];
    const int t = threadIdx.x;
    const int w = t >> 6, l = t & 63;
    const int row0 = w * 16;
    const int n0 = blockIdx.x * NTILE;

    {
        int row = t >> 2, part = t & 3;
        int n = n0 + row;
        bool valid = n < N_NODES;
        if (part == 3) s_batch[row] = valid ? batch[n] : -1;
        #pragma unroll
        for (int gi = 0; gi < 4; gi++) {
            int g = part * 4 + gi;
            bf16x8 pk;
            #pragma unroll
            for (int j = 0; j < 8; j++) pk[j] = (bf16_t)0.f;
            if (valid && g < 9) {
                const float* sp = (g < 3) ? f0 + (size_t)n*EMB + 8*g
                                : (g < 6) ? f1 + (size_t)n*EMB + 8*(g-3)
                                          : f2 + (size_t)n*EMB + 8*(g-6);
                float4 a = ((const float4*)sp)[0], b = ((const float4*)sp)[1];
                pk[0]=(bf16_t)siluf(a.x); pk[1]=(bf16_t)siluf(a.y);
                pk[2]=(bf16_t)siluf(a.z); pk[3]=(bf16_t)siluf(a.w);
                pk[4]=(bf16_t)siluf(b.x); pk[5]=(bf16_t)siluf(b.y);
                pk[6]=(bf16_t)siluf(b.z); pk[7]=(bf16_t)siluf(b.w);
            }
            *(bf16x8*)&sH[row*128 + (g ^ (row & 7))*8] = pk;
        }
    }
    __syncthreads();

    bf16x8 a0[4];
    {
        int r = row0 + (l & 15);
        #pragma unroll
        for (int ks = 0; ks < 4; ks++)
            a0[ks] = *(const bf16x8*)&sH[r*128 + ((ks*4 + (l >> 4)) ^ (r & 7))*8];
    }
    __syncthreads();

    f32x4 acc[16];
    #pragma unroll
    for (int nt = 0; nt < 16; nt++) {
        float bv = b0[nt*16 + (l & 15)];
        acc[nt] = (f32x4){bv, bv, bv, bv};
    }
    #pragma unroll
    for (int ks = 0; ks < 4; ks++)
        #pragma unroll
        for (int nt = 0; nt < 16; nt++) {
            int n = nt*16 + (l & 15);
            bf16x8 b = *(const bf16x8*)&W0p[n*128 + (ks*4 + (l >> 4))*8];
            acc[nt] = __builtin_amdgcn_mfma_f32_16x16x32_bf16(a0[ks], b, acc[nt], 0, 0, 0);
        }
    #pragma unroll
    for (int nt = 0; nt < 16; nt++)
        #pragma unroll
        for (int r4 = 0; r4 < 4; r4++) {
            int row = row0 + (l >> 4)*4 + r4;
            int col = nt*16 + (l & 15);
            sH[row*256 + ((col >> 3) ^ (row & 7))*8 + (col & 7)] = (bf16_t)siluf(acc[nt][r4]);
        }
    __syncthreads();

    #pragma unroll
    for (int layer = 0; layer < 2; layer++) {
        const bf16_t* Wp = layer ? W2p : W1p;
        const float*  bb = layer ? b2  : b1;
        #pragma unroll
        for (int nt = 0; nt < 16; nt++) {
            float bv = bb[nt*16 + (l & 15)];
            acc[nt] = (f32x4){bv, bv, bv, bv};
        }
        for (int ks = 0; ks < 8; ks++) {
            int r = row0 + (l & 15);
            bf16x8 a = *(const bf16x8*)&sH[r*256 + ((ks*4 + (l >> 4)) ^ (r & 7))*8];
            #pragma unroll
            for (int nt = 0; nt < 16; nt++) {
                int n = nt*16 + (l & 15);
                bf16x8 b = *(const bf16x8*)&Wp[n*256 + (ks*4 + (l >> 4))*8];
                acc[nt] = __builtin_amdgcn_mfma_f32_16x16x32_bf16(a, b, acc[nt], 0, 0, 0);
            }
        }
        __syncthreads();
        #pragma unroll
        for (int nt = 0; nt < 16; nt++)
            #pragma unroll
            for (int r4 = 0; r4 < 4; r4++) {
                int row = row0 + (l >> 4)*4 + r4;
                int col = nt*16 + (l & 15);
                sH[row*256 + ((col >> 3) ^ (row & 7))*8 + (col & 7)] = (bf16_t)siluf(acc[nt][r4]);
            }
        __syncthreads();
    }

    {
        int j = t;
        int g = j >> 3, jo = j & 7;
        int cur = -1;
        float run = 0.f;
        for (int i = 0; i < NTILE; i++) {
            int bb = s_batch[i];
            if (bb != cur) {
                if (cur >= 0) atomicAdd(&pooled[cur * MLP + j], run);
                run = 0.f; cur = bb;
            }
            if (bb >= 0) run += (float)sH[i*256 + (g ^ (i & 7))*8 + jo];
        }
        if (cur >= 0) atomicAdd(&pooled[cur * MLP + j], run);
    }
}

// ---------------- final: sigmoid((pooled/cnt) @ fow + fob) ------------------
__global__ void final_kernel(const float* __restrict__ pooled, const float* __restrict__ cnt,
                             const float* __restrict__ fow, const float* __restrict__ fob,
                             float* __restrict__ out)
{
    int t = threadIdx.x;
    int bg = t >> 2, o = t & 3;
    float c = fmaxf(cnt[bg], 1.0f);
    float acc = 0.f;
    for (int i = 0; i < MLP; i++) acc = fmaf(pooled[bg * MLP + i], fow[i * 4 + o], acc);
    acc = acc / c + fob[o];
    out[t] = 1.0f / (1.0f + __expf(-acc));
}

extern "C" void kernel_launch(void* const* d_in, const int* in_sizes, int n_in,
                              void* d_out, int out_size, void* d_ws, size_t ws_size,
                              hipStream_t stream)
{
    const int*   z     = (const int*)  d_in[0];
    const float* pos   = (const float*)d_in[1];
    const int*   eidx  = (const int*)  d_in[2];
    const int*   batch = (const int*)  d_in[3];
    const float* embt  = (const float*)d_in[4];
    const float* embw  = (const float*)d_in[5];
    const float* embb  = (const float*)d_in[6];
    const float* ew1   = (const float*)d_in[7];
    const float* eb1   = (const float*)d_in[8];
    const float* ew2   = (const float*)d_in[9];
    const float* eb2   = (const float*)d_in[10];
    const float* cw1   = (const float*)d_in[11];
    const float* cb1   = (const float*)d_in[12];
    const float* cw2   = (const float*)d_in[13];
    const float* cb2   = (const float*)d_in[14];
    const float* nw1   = (const float*)d_in[15];
    const float* nb1   = (const float*)d_in[16];
    const float* nw2   = (const float*)d_in[17];
    const float* nb2   = (const float*)d_in[18];
    const float* f0w   = (const float*)d_in[19];
    const float* f0b   = (const float*)d_in[20];
    const float* f1w   = (const float*)d_in[21];
    const float* f1b   = (const float*)d_in[22];
    const float* f2w   = (const float*)d_in[23];
    const float* f2b   = (const float*)d_in[24];
    const float* fow   = (const float*)d_in[25];
    const float* fob   = (const float*)d_in[26];

    float* ws     = (float*)d_ws;
    float* f0     = ws;                                   // 1.2M floats
    float* f1v    = f0 + (size_t)N_NODES * EMB;
    float* f2v    = f1v + (size_t)N_NODES * EMB;
    bf16_t* fb0   = (bf16_t*)(f2v + (size_t)N_NODES * EMB); // 1.2M bf16 = 300k floats
    bf16_t* fb1   = fb0 + (size_t)N_NODES * EMB;
    float* coorsA = (float*)(fb1 + (size_t)N_NODES * EMB);
    float* cdelta = coorsA + N_NODES * 3;
    float* m_i    = cdelta + N_NODES * 3;
    float* pooled = m_i + (size_t)N_NODES * MDIM;
    float* cnt    = pooled + N_GRAPHS * MLP;
    int*   deg    = (int*)(cnt + N_GRAPHS);
    int*   cursor = deg + N_NODES;
    int*   srcs_s = cursor + N_NODES;
    int*   dsts_s = srcs_s + N_EDGES;
    bf16_t* packw = (bf16_t*)(dsts_s + N_EDGES);
    bf16_t* W1t0  = packw;
    bf16_t* W1t1  = W1t0 + PK_W1;
    bf16_t* W2t0  = W1t1 + PK_W1;
    bf16_t* W2t1  = W2t0 + PK_W2;
    bf16_t* CW1t  = W2t1 + PK_W2;
    bf16_t* W0p   = CW1t + PK_CW;
    bf16_t* W1p   = W0p + PK_F0;
    bf16_t* W2p   = W1p + PK_FM;

    hipMemsetAsync(cdelta, 0, N_NODES * 3 * sizeof(float), stream);
    hipMemsetAsync(m_i, 0, (size_t)N_NODES * MDIM * sizeof(float), stream);
    hipMemsetAsync(pooled, 0, (N_GRAPHS * MLP + N_GRAPHS) * sizeof(float), stream);
    hipMemsetAsync(deg, 0, N_NODES * sizeof(int), stream);

    const int* e_src = eidx;
    const int* e_dst = eidx + N_EDGES;
    pack_kernel<<<(PK_TOT + 255) / 256, 256, 0, stream>>>(ew1, eb1, ew2, eb2, cw1,
                                                          f0w, f1w, f2w, packw);
    hist_kernel<<<(N_EDGES + 255) / 256, 256, 0, stream>>>(e_dst, deg);
    scan_kernel<<<1, 1024, 0, stream>>>(deg, cursor);
    scatter_kernel<<<(N_EDGES + 255) / 256, 256, 0, stream>>>(e_src, e_dst, cursor, srcs_s, dsts_s);

    embed_kernel<<<(N_NODES + 255) / 256, 256, 0, stream>>>(z, embt, embw, embb, batch, f0, fb0, cnt);

    const int EBLK = N_EDGES / ETILE; // 6250
    edge_mfma<1><<<EBLK, 256, 0, stream>>>(fb0, pos, srcs_s, dsts_s,
        W1t0, W2t0, CW1t, cb1, cw2, cb2, m_i, cdelta);
    node_kernel<1><<<(N_NODES + 255) / 256, 256, 0, stream>>>(f0, m_i, nw1, nb1, nw2, nb2, f1v, fb1);
    coor_kernel<<<(N_NODES * 3 + 255) / 256, 256, 0, stream>>>(pos, cdelta, coorsA);
    hipMemsetAsync(m_i, 0, (size_t)N_NODES * MDIM * sizeof(float), stream);
    edge_mfma<0><<<EBLK, 256, 0, stream>>>(fb1, coorsA, srcs_s, dsts_s,
        W1t1, W2t1, CW1t, cb1, cw2, cb2, m_i, nullptr);
    node_kernel<0><<<(N_NODES + 255) / 256, 256, 0, stream>>>(f1v, m_i,
        nw1 + NIN * NH, nb1 + NH, nw2 + NH * EMB, nb2 + EMB, f2v, nullptr);

    const int FBLK = (N_NODES + NTILE - 1) / NTILE;
    ffnn_fused<<<FBLK, 256, 0, stream>>>(f0, f1v, f2v, W0p, W1p, W2p,
                                         f0b, f1b, f2b, batch, pooled);

    final_kernel<<<1, 256, 0, stream>>>(pooled, cnt, fow, fob, (float*)d_out);
}

// Round 5
// 995.418 us; speedup vs baseline: 6.9807x; 1.1098x over previous
//
#include <hip/hip_runtime.h>
#include <hip/hip_bf16.h>

#define N_NODES  50000
#define N_EDGES  800000
#define N_GRAPHS 64
#define EMB      24
#define MDIM     64
#define EDGE_IN  57
#define EH       114   // EDGE_IN*2
#define CH       256   // M_DIM*4
#define NIN      88    // EMB+MDIM
#define NH       48    // EMB*2
#define MLP      256
#define ETILE    128
#define NTILE    64

typedef __bf16 bf16_t;
typedef __bf16 bf16x8 __attribute__((ext_vector_type(8)));
typedef __bf16 bf16x4 __attribute__((ext_vector_type(4)));
typedef float  f32x4  __attribute__((ext_vector_type(4)));

__device__ __forceinline__ float siluf(float x) {
    return x * __builtin_amdgcn_rcpf(1.0f + __expf(-x));
}

// ---------------- embedding: feats0 = emb_table[z] @ emb_w + emb_b ----------
__global__ void embed_kernel(const int* __restrict__ z, const float* __restrict__ table,
                             const float* __restrict__ w, const float* __restrict__ b,
                             const int* __restrict__ batch, float* __restrict__ f0,
                             bf16_t* __restrict__ fb0, float* __restrict__ cnt)
{
    int n = blockIdx.x * blockDim.x + threadIdx.x;
    if (n >= N_NODES) return;
    float r[EMB];
    const float4* tr = reinterpret_cast<const float4*>(table + z[n] * EMB);
    #pragma unroll
    for (int q = 0; q < 6; q++) {
        float4 v = tr[q];
        r[q*4] = v.x; r[q*4+1] = v.y; r[q*4+2] = v.z; r[q*4+3] = v.w;
    }
    float o[EMB];
    #pragma unroll
    for (int j = 0; j < EMB; j++) o[j] = b[j];
    #pragma unroll
    for (int i = 0; i < EMB; i++) {
        #pragma unroll
        for (int j = 0; j < EMB; j++) o[j] = fmaf(r[i], w[i*EMB + j], o[j]);
    }
    float4* dst = reinterpret_cast<float4*>(f0 + (size_t)n * EMB);
    #pragma unroll
    for (int q = 0; q < 6; q++) dst[q] = make_float4(o[q*4], o[q*4+1], o[q*4+2], o[q*4+3]);
    bf16x8* bdst = reinterpret_cast<bf16x8*>(fb0 + (size_t)n * EMB);
    #pragma unroll
    for (int q = 0; q < 3; q++) {
        bf16x8 pk;
        #pragma unroll
        for (int j = 0; j < 8; j++) pk[j] = (bf16_t)o[q*8 + j];
        bdst[q] = pk;
    }
    atomicAdd(&cnt[batch[n]], 1.0f);
}

// ---------------- weight pre-pack to bf16 MFMA layout (A-operand [n][k]) ----
#define PK_W1   (128*64)
#define PK_W2   (64*128)
#define PK_CW   (256*64)
#define PK_F0   (256*128)
#define PK_FM   (256*256)
#define PK_TOT  (2*PK_W1 + 2*PK_W2 + PK_CW + PK_F0 + 2*PK_FM)
__global__ void pack_kernel(const float* __restrict__ ew1, const float* __restrict__ eb1,
                            const float* __restrict__ ew2, const float* __restrict__ eb2,
                            const float* __restrict__ cw1, const float* __restrict__ f0w,
                            const float* __restrict__ f1w, const float* __restrict__ f2w,
                            bf16_t* __restrict__ pw)
{
    int idx = blockIdx.x * blockDim.x + threadIdx.x;
    if (idx >= PK_TOT) return;
    float v = 0.0f;
    if (idx < 2 * PK_W1) {
        int l = idx / PK_W1, r = idx - l * PK_W1;
        int n = r >> 6, k = r & 63;
        if (n < EH && k < EDGE_IN)       v = ew1[(l * EDGE_IN + k) * EH + n];
        else if (n < EH && k == EDGE_IN) v = eb1[l * EH + n];
    } else if (idx < 2 * PK_W1 + 2 * PK_W2) {
        int r0 = idx - 2 * PK_W1;
        int l = r0 / PK_W2, r = r0 - l * PK_W2;
        int n = r >> 7, k = r & 127;
        if (k < EH)       v = ew2[(l * EH + k) * MDIM + n];
        else if (k == EH) v = eb2[l * MDIM + n];
    } else if (idx < 2 * PK_W1 + 2 * PK_W2 + PK_CW) {
        int r = idx - (2 * PK_W1 + 2 * PK_W2);
        int n = r >> 6, k = r & 63;
        v = cw1[k * CH + n];
    } else if (idx < 2 * PK_W1 + 2 * PK_W2 + PK_CW + PK_F0) {
        int r = idx - (2 * PK_W1 + 2 * PK_W2 + PK_CW);
        int n = r >> 7, k = r & 127;
        if (k < 72) v = f0w[k * MLP + n];
    } else {
        int r0 = idx - (2 * PK_W1 + 2 * PK_W2 + PK_CW + PK_F0);
        int l = r0 / PK_FM, r = r0 - l * PK_FM;
        int n = r >> 8, k = r & 255;
        v = (l == 0) ? f1w[k * MLP + n] : f2w[k * MLP + n];
    }
    pw[idx] = (bf16_t)v;
}

// ---------------- CSR build --------------------------------------------------
__global__ void hist_kernel(const int* __restrict__ dst, int* __restrict__ deg)
{
    int e = blockIdx.x * blockDim.x + threadIdx.x;
    if (e < N_EDGES) atomicAdd(&deg[dst[e]], 1);
}

__global__ __launch_bounds__(1024)
void scan_kernel(const int* __restrict__ deg, int* __restrict__ cursor)
{
    __shared__ int part[1024];
    int t = threadIdx.x;
    const int PER = 49;
    int base = t * PER;
    int s = 0;
    for (int i = 0; i < PER; i++) {
        int p = base + i;
        if (p < N_NODES) s += deg[p];
    }
    part[t] = s;
    __syncthreads();
    for (int off = 1; off < 1024; off <<= 1) {
        int add = (t >= off) ? part[t - off] : 0;
        __syncthreads();
        part[t] += add;
        __syncthreads();
    }
    int run = (t > 0) ? part[t - 1] : 0;
    for (int i = 0; i < PER; i++) {
        int p = base + i;
        if (p < N_NODES) { cursor[p] = run; run += deg[p]; }
    }
}

__global__ void scatter_kernel(const int* __restrict__ src, const int* __restrict__ dst,
                               int* __restrict__ cursor, int* __restrict__ srcs_s,
                               int* __restrict__ dsts_s)
{
    int e = blockIdx.x * blockDim.x + threadIdx.x;
    if (e >= N_EDGES) return;
    int d = dst[e];
    int pos = atomicAdd(&cursor[d], 1);
    srcs_s[pos] = src[e];
    dsts_s[pos] = d;
}

// ---------------- fused MFMA edge kernel (transposed GEMMs) -----------------
// 256 thr / 4 waves, 128 edges. A = weights [n][k] (global, L2-hot),
// B = data^T (LDS). D = out^T: lane holds 4 consecutive features of one edge.
// cdelta: per-edge cacc staged in LDS, run-reduced (dst-sorted) -> ~27
// atomics/block instead of 384 (kills the degree-16 same-address chains).
template<int COOR>
__global__ __launch_bounds__(256, 4)
void edge_mfma(const bf16_t* __restrict__ fb, const float* __restrict__ coors,
               const int* __restrict__ srcs_s, const int* __restrict__ dsts_s,
               const bf16_t* __restrict__ W1t, const bf16_t* __restrict__ W2t,
               const bf16_t* __restrict__ CW1t, const float* __restrict__ cb1,
               const float* __restrict__ cw2, const float* __restrict__ cb2,
               float* __restrict__ m_i, float* __restrict__ cdelta)
{
    __shared__ __align__(16) char R1raw[ETILE * 64 * 4]; // 32KB
    __shared__ float s_rel[COOR ? ETILE * 3 : 4];
    __shared__ float s_cacc[COOR ? ETILE : 4];
    __shared__ int   s_dst[ETILE];
    bf16_t* R1 = (bf16_t*)R1raw;
    float*  Mf32 = (float*)R1raw;

    const int t = threadIdx.x;
    const int w = t >> 6;
    const int l = t & 63;
    const int row0 = w * 32;          // wave's 32-edge stripe
    const int ebase = blockIdx.x * ETILE;
    const int l15 = l & 15, l4 = l >> 4;

    // ---- gather: 2 threads per edge, bf16 feats ----
    {
        int e_loc = t >> 1, half = t & 1;
        int e = ebase + e_loc;
        int s = srcs_s[e], d = dsts_s[e];
        if (half == 0) {
            s_dst[e_loc] = d;
            const bf16x8* fp = reinterpret_cast<const bf16x8*>(fb + (size_t)d * EMB);
            #pragma unroll
            for (int g = 0; g < 3; g++)
                *(bf16x8*)&R1[e_loc*64 + (g ^ (e_loc & 7))*8] = fp[g];
        } else {
            const bf16x8* fp = reinterpret_cast<const bf16x8*>(fb + (size_t)s * EMB);
            #pragma unroll
            for (int g = 0; g < 3; g++)
                *(bf16x8*)&R1[e_loc*64 + ((g + 3) ^ (e_loc & 7))*8] = fp[g];
            float rx = coors[s*3+0] - coors[d*3+0];
            float ry = coors[s*3+1] - coors[d*3+1];
            float rz = coors[s*3+2] - coors[d*3+2];
            float d2 = rx*rx + ry*ry + rz*rz;
            if (COOR) { s_rel[e_loc*3+0] = rx; s_rel[e_loc*3+1] = ry; s_rel[e_loc*3+2] = rz; }
            bf16x8 p6, p7;
            p6[0]=(bf16_t)__sinf(d2);        p6[1]=(bf16_t)__sinf(d2*0.5f);
            p6[2]=(bf16_t)__sinf(d2*0.25f);  p6[3]=(bf16_t)__sinf(d2*0.125f);
            p6[4]=(bf16_t)__cosf(d2);        p6[5]=(bf16_t)__cosf(d2*0.5f);
            p6[6]=(bf16_t)__cosf(d2*0.25f);  p6[7]=(bf16_t)__cosf(d2*0.125f);
            p7[0]=(bf16_t)d2; p7[1]=(bf16_t)1.0f;
            p7[2]=(bf16_t)0.f; p7[3]=(bf16_t)0.f; p7[4]=(bf16_t)0.f;
            p7[5]=(bf16_t)0.f; p7[6]=(bf16_t)0.f; p7[7]=(bf16_t)0.f;
            *(bf16x8*)&R1[e_loc*64 + (6 ^ (e_loc & 7))*8] = p6;
            *(bf16x8*)&R1[e_loc*64 + (7 ^ (e_loc & 7))*8] = p7;
        }
    }
    __syncthreads();

    // ---- GEMM1: H1^T[f][e] = W1t[f][k] * Ein^T[k][e] ----
    f32x4 acc1[2][8];
    #pragma unroll
    for (int et = 0; et < 2; et++)
        #pragma unroll
        for (int ft = 0; ft < 8; ft++) acc1[et][ft] = (f32x4){0.f,0.f,0.f,0.f};
    #pragma unroll
    for (int ks = 0; ks < 2; ks++) {
        bf16x8 bfrag[2];
        #pragma unroll
        for (int et = 0; et < 2; et++) {
            int e = row0 + et*16 + l15;
            bfrag[et] = *(const bf16x8*)&R1[e*64 + ((ks*4 + l4) ^ (e & 7))*8];
        }
        #pragma unroll
        for (int ft = 0; ft < 8; ft++) {
            bf16x8 a = *(const bf16x8*)&W1t[(ft*16 + l15)*64 + (ks*4 + l4)*8];
            acc1[0][ft] = __builtin_amdgcn_mfma_f32_16x16x32_bf16(a, bfrag[0], acc1[0][ft], 0, 0, 0);
            acc1[1][ft] = __builtin_amdgcn_mfma_f32_16x16x32_bf16(a, bfrag[1], acc1[1][ft], 0, 0, 0);
        }
    }
    __syncthreads();
    // write H1[e][f] = silu; f==114 -> 1.0 (GEMM2 bias slot); b64 stores
    #pragma unroll
    for (int et = 0; et < 2; et++)
        #pragma unroll
        for (int ft = 0; ft < 8; ft++) {
            int e = row0 + et*16 + l15;
            int f0 = ft*16 + l4*4;
            bf16x4 pk;
            #pragma unroll
            for (int r4 = 0; r4 < 4; r4++) {
                float hv = siluf(acc1[et][ft][r4]);
                if (f0 + r4 == EH) hv = 1.0f;
                pk[r4] = (bf16_t)hv;
            }
            *(bf16x4*)&R1[e*128 + ((f0 >> 3) ^ (e & 7))*8 + (f0 & 7)] = pk;
        }
    __syncthreads();

    // ---- GEMM2: M^T[f][e] = W2t[f][k] * H1^T[k][e] ----
    f32x4 acc2[2][4];
    #pragma unroll
    for (int et = 0; et < 2; et++)
        #pragma unroll
        for (int ft = 0; ft < 4; ft++) acc2[et][ft] = (f32x4){0.f,0.f,0.f,0.f};
    #pragma unroll
    for (int ks = 0; ks < 4; ks++) {
        bf16x8 bfrag[2];
        #pragma unroll
        for (int et = 0; et < 2; et++) {
            int e = row0 + et*16 + l15;
            bfrag[et] = *(const bf16x8*)&R1[e*128 + ((ks*4 + l4) ^ (e & 7))*8];
        }
        #pragma unroll
        for (int ft = 0; ft < 4; ft++) {
            bf16x8 a = *(const bf16x8*)&W2t[(ft*16 + l15)*128 + (ks*4 + l4)*8];
            acc2[0][ft] = __builtin_amdgcn_mfma_f32_16x16x32_bf16(a, bfrag[0], acc2[0][ft], 0, 0, 0);
            acc2[1][ft] = __builtin_amdgcn_mfma_f32_16x16x32_bf16(a, bfrag[1], acc2[1][ft], 0, 0, 0);
        }
    }
    __syncthreads();
    // write M[e][f] f32 (swizzled 16B granules), b128 stores
    #pragma unroll
    for (int et = 0; et < 2; et++)
        #pragma unroll
        for (int ft = 0; ft < 4; ft++) {
            int e = row0 + et*16 + l15;
            int f0 = ft*16 + l4*4;
            f32x4 v;
            #pragma unroll
            for (int r4 = 0; r4 < 4; r4++) v[r4] = siluf(acc2[et][ft][r4]);
            *(f32x4*)&Mf32[e*64 + (((f0 >> 2) ^ (e & 7)) << 2)] = v;
        }
    __syncthreads();

    // ---- m_i run-reduction (dst-sorted; 32-edge groups per wave) ----
    {
        int col = t & 63;
        int gsw_base = col >> 2, cw = col & 3;
        int gb = w * 32;
        int cur = s_dst[gb];
        float run = 0.f;
        for (int i = 0; i < 32; i++) {
            int row = gb + i;
            int d = s_dst[row];
            float v = Mf32[row*64 + ((gsw_base ^ (row & 7)) << 2) + cw];
            if (d != cur) { atomicAdd(&m_i[(size_t)cur*64 + col], run); run = 0.f; cur = d; }
            run += v;
        }
        atomicAdd(&m_i[(size_t)cur*64 + col], run);
    }

    // ---- GEMM3 + run-reduced coor scatter (layer 0 only) ----
    if (COOR) {
        float csum[2] = {0.f, 0.f};
        #pragma unroll
        for (int half = 0; half < 2; half++) {
            f32x4 acc3[2][8];
            #pragma unroll
            for (int et = 0; et < 2; et++)
                #pragma unroll
                for (int ft = 0; ft < 8; ft++) acc3[et][ft] = (f32x4){0.f,0.f,0.f,0.f};
            #pragma unroll
            for (int ks = 0; ks < 2; ks++) {
                bf16x8 bfrag[2];
                #pragma unroll
                for (int et = 0; et < 2; et++) {
                    int e = row0 + et*16 + l15;
                    int g0 = (ks*4 + l4) * 2;   // f32 16B-granule index (even)
                    f32x4 lo = *(const f32x4*)&Mf32[e*64 + ((g0 ^ (e & 7)) << 2)];
                    f32x4 hi = *(const f32x4*)&Mf32[e*64 + (((g0 + 1) ^ (e & 7)) << 2)];
                    bf16x8 bk;
                    #pragma unroll
                    for (int j = 0; j < 4; j++) { bk[j] = (bf16_t)lo[j]; bk[j+4] = (bf16_t)hi[j]; }
                    bfrag[et] = bk;
                }
                #pragma unroll
                for (int ft = 0; ft < 8; ft++) {
                    bf16x8 a = *(const bf16x8*)&CW1t[(half*128 + ft*16 + l15)*64 + (ks*4 + l4)*8];
                    acc3[0][ft] = __builtin_amdgcn_mfma_f32_16x16x32_bf16(a, bfrag[0], acc3[0][ft], 0, 0, 0);
                    acc3[1][ft] = __builtin_amdgcn_mfma_f32_16x16x32_bf16(a, bfrag[1], acc3[1][ft], 0, 0, 0);
                }
            }
            #pragma unroll
            for (int ft = 0; ft < 8; ft++) {
                int f0 = half*128 + ft*16 + l4*4;
                float4 c1 = *(const float4*)&cb1[f0];
                float4 w2 = *(const float4*)&cw2[f0];
                #pragma unroll
                for (int et = 0; et < 2; et++) {
                    csum[et] = fmaf(siluf(acc3[et][ft][0] + c1.x), w2.x, csum[et]);
                    csum[et] = fmaf(siluf(acc3[et][ft][1] + c1.y), w2.y, csum[et]);
                    csum[et] = fmaf(siluf(acc3[et][ft][2] + c1.z), w2.z, csum[et]);
                    csum[et] = fmaf(siluf(acc3[et][ft][3] + c1.w), w2.w, csum[et]);
                }
            }
        }
        #pragma unroll
        for (int et = 0; et < 2; et++) {
            csum[et] += __shfl_xor(csum[et], 16);
            csum[et] += __shfl_xor(csum[et], 32);
        }
        if (l < 16) {
            float cb2v = cb2[0];
            s_cacc[row0 + l]      = csum[0] + cb2v;
            s_cacc[row0 + 16 + l] = csum[1] + cb2v;
        }
        __syncthreads();
        // run-reduce cdelta: one head thread per dst-run, ~9 runs/block
        if (t < ETILE) {
            int d = s_dst[t];
            bool head = (t == 0) || (s_dst[t-1] != d);
            if (head) {
                float ax = 0.f, ay = 0.f, az = 0.f;
                int i = t;
                do {
                    float c = s_cacc[i];
                    ax = fmaf(c, s_rel[i*3+0], ax);
                    ay = fmaf(c, s_rel[i*3+1], ay);
                    az = fmaf(c, s_rel[i*3+2], az);
                    ++i;
                } while (i < ETILE && s_dst[i] == d);
                atomicAdd(&cdelta[d*3+0], ax);
                atomicAdd(&cdelta[d*3+1], ay);
                atomicAdd(&cdelta[d*3+2], az);
            }
        }
    }
}

// ---------------- node kernel: feats_out = feats + MLP([feats, m_i]) --------
template<int EMIT_BF16>
__global__ __launch_bounds__(256)
void node_kernel(const float* __restrict__ feats, const float* __restrict__ m_i,
                 const float* __restrict__ nw1, const float* __restrict__ nb1,
                 const float* __restrict__ nw2, const float* __restrict__ nb2,
                 float* __restrict__ fout, bf16_t* __restrict__ fbout)
{
    __shared__ float s_w1t[NH * NIN];
    __shared__ float s_b1[NH];
    __shared__ float s_w2[NH * EMB];
    __shared__ float s_b2[EMB];
    const int tid = threadIdx.x;
    for (int idx = tid; idx < NH * NIN; idx += 256) {
        int k = idx / NIN, i = idx - k * NIN;
        s_w1t[idx] = nw1[i * NH + k];
    }
    for (int idx = tid; idx < NH * EMB; idx += 256) s_w2[idx] = nw2[idx];
    if (tid < NH) s_b1[tid] = nb1[tid];
    if (tid < EMB) s_b2[tid] = nb2[tid];
    __syncthreads();

    int n = blockIdx.x * 256 + tid;
    if (n >= N_NODES) return;

    float in[NIN];
    const float4* fp = reinterpret_cast<const float4*>(feats + (size_t)n * EMB);
    #pragma unroll
    for (int q = 0; q < 6; q++) {
        float4 v = fp[q];
        in[q*4] = v.x; in[q*4+1] = v.y; in[q*4+2] = v.z; in[q*4+3] = v.w;
    }
    const float4* mp = reinterpret_cast<const float4*>(m_i + (size_t)n * MDIM);
    #pragma unroll
    for (int q = 0; q < 16; q++) {
        float4 v = mp[q];
        in[EMB+q*4] = v.x; in[EMB+q*4+1] = v.y; in[EMB+q*4+2] = v.z; in[EMB+q*4+3] = v.w;
    }
    float o[EMB];
    #pragma unroll
    for (int j = 0; j < EMB; j++) o[j] = in[j] + s_b2[j];
    for (int k = 0; k < NH; k++) {
        const float* w1 = &s_w1t[k * NIN];
        float a0 = 0.f, a1 = 0.f, a2 = 0.f, a3 = 0.f;
        #pragma unroll
        for (int i = 0; i < NIN; i += 4) {
            a0 = fmaf(in[i],   w1[i],   a0);
            a1 = fmaf(in[i+1], w1[i+1], a1);
            a2 = fmaf(in[i+2], w1[i+2], a2);
            a3 = fmaf(in[i+3], w1[i+3], a3);
        }
        float h = siluf(s_b1[k] + ((a0 + a1) + (a2 + a3)));
        const float* w2 = &s_w2[k * EMB];
        #pragma unroll
        for (int j = 0; j < EMB; j++) o[j] = fmaf(h, w2[j], o[j]);
    }
    float4* dst = reinterpret_cast<float4*>(fout + (size_t)n * EMB);
    #pragma unroll
    for (int q = 0; q < 6; q++) dst[q] = make_float4(o[q*4], o[q*4+1], o[q*4+2], o[q*4+3]);
    if (EMIT_BF16) {
        bf16x8* bdst = reinterpret_cast<bf16x8*>(fbout + (size_t)n * EMB);
        #pragma unroll
        for (int q = 0; q < 3; q++) {
            bf16x8 pk;
            #pragma unroll
            for (int j = 0; j < 8; j++) pk[j] = (bf16_t)o[q*8 + j];
            bdst[q] = pk;
        }
    }
}

// ---------------- coors update ----------------------------------------------
__global__ void coor_kernel(const float* __restrict__ pos, const float* __restrict__ cdelta,
                            float* __restrict__ out)
{
    int i = blockIdx.x * blockDim.x + threadIdx.x;
    if (i < N_NODES * 3) out[i] = pos[i] + cdelta[i];
}

// ---------------- fused MFMA FFNN: 512 thr / 8 waves (4 M-tiles x 2 N-halves)
__global__ __launch_bounds__(512, 4)
void ffnn_fused(const float* __restrict__ f0, const float* __restrict__ f1,
                const float* __restrict__ f2,
                const bf16_t* __restrict__ W0p, const bf16_t* __restrict__ W1p,
                const bf16_t* __restrict__ W2p,
                const float* __restrict__ b0, const float* __restrict__ b1,
                const float* __restrict__ b2,
                const int* __restrict__ batch, float* __restrict__ pooled)
{
    __shared__ __align__(16) bf16_t sH[NTILE * 256]; // 32KB
    __shared__ int s_batch[NTILE];
    const int t = threadIdx.x;
    const int w = t >> 6, l = t & 63;
    const int l15 = l & 15, q = l >> 4;
    const int mt = w & 3;          // M-tile (16 nodes)
    const int nh = w >> 2;         // N-half (8 nt of 16)
    const int mrow0 = mt * 16;
    const int n0 = blockIdx.x * NTILE;

    // ---- gather x = silu(concat(f0,f1,f2)) -> sH-as-[64][128] bf16 swz ----
    {
        int row = t >> 3, part = t & 7;
        int n = n0 + row;
        bool valid = n < N_NODES;
        if (part == 7) s_batch[row] = valid ? batch[n] : -1;
        #pragma unroll
        for (int gi = 0; gi < 2; gi++) {
            int g = part * 2 + gi;
            bf16x8 pk;
            #pragma unroll
            for (int j = 0; j < 8; j++) pk[j] = (bf16_t)0.f;
            if (valid && g < 9) {
                const float* sp = (g < 3) ? f0 + (size_t)n*EMB + 8*g
                                : (g < 6) ? f1 + (size_t)n*EMB + 8*(g-3)
                                          : f2 + (size_t)n*EMB + 8*(g-6);
                float4 a = ((const float4*)sp)[0], b = ((const float4*)sp)[1];
                pk[0]=(bf16_t)siluf(a.x); pk[1]=(bf16_t)siluf(a.y);
                pk[2]=(bf16_t)siluf(a.z); pk[3]=(bf16_t)siluf(a.w);
                pk[4]=(bf16_t)siluf(b.x); pk[5]=(bf16_t)siluf(b.y);
                pk[6]=(bf16_t)siluf(b.z); pk[7]=(bf16_t)siluf(b.w);
            }
            *(bf16x8*)&sH[row*128 + (g ^ (row & 7))*8] = pk;
        }
    }
    __syncthreads();

    // ---- L0: prefetch A to regs, then h = silu(x @ W0p + b0) ----
    bf16x8 a0[4];
    {
        int r = mrow0 + l15;
        #pragma unroll
        for (int ks = 0; ks < 4; ks++)
            a0[ks] = *(const bf16x8*)&sH[r*128 + ((ks*4 + q) ^ (r & 7))*8];
    }
    __syncthreads();   // all x reads done before sH is overwritten

    f32x4 acc[8];
    #pragma unroll
    for (int nt = 0; nt < 8; nt++) {
        float bv = b0[(nh*8 + nt)*16 + l15];
        acc[nt] = (f32x4){bv, bv, bv, bv};
    }
    #pragma unroll
    for (int ks = 0; ks < 4; ks++)
        #pragma unroll
        for (int nt = 0; nt < 8; nt++) {
            int n = (nh*8 + nt)*16 + l15;
            bf16x8 b = *(const bf16x8*)&W0p[n*128 + (ks*4 + q)*8];
            acc[nt] = __builtin_amdgcn_mfma_f32_16x16x32_bf16(a0[ks], b, acc[nt], 0, 0, 0);
        }
    #pragma unroll
    for (int nt = 0; nt < 8; nt++)
        #pragma unroll
        for (int r4 = 0; r4 < 4; r4++) {
            int row = mrow0 + q*4 + r4;
            int col = (nh*8 + nt)*16 + l15;
            sH[row*256 + ((col >> 3) ^ (row & 7))*8 + (col & 7)] = (bf16_t)siluf(acc[nt][r4]);
        }
    __syncthreads();

    // ---- L1 and L2: h = silu(h @ Wp + b) ----
    #pragma unroll
    for (int layer = 0; layer < 2; layer++) {
        const bf16_t* Wp = layer ? W2p : W1p;
        const float*  bb = layer ? b2  : b1;
        #pragma unroll
        for (int nt = 0; nt < 8; nt++) {
            float bv = bb[(nh*8 + nt)*16 + l15];
            acc[nt] = (f32x4){bv, bv, bv, bv};
        }
        for (int ks = 0; ks < 8; ks++) {
            int r = mrow0 + l15;
            bf16x8 a = *(const bf16x8*)&sH[r*256 + ((ks*4 + q) ^ (r & 7))*8];
            #pragma unroll
            for (int nt = 0; nt < 8; nt++) {
                int n = (nh*8 + nt)*16 + l15;
                bf16x8 b = *(const bf16x8*)&Wp[n*256 + (ks*4 + q)*8];
                acc[nt] = __builtin_amdgcn_mfma_f32_16x16x32_bf16(a, b, acc[nt], 0, 0, 0);
            }
        }
        __syncthreads();   // all h reads done before overwrite
        #pragma unroll
        for (int nt = 0; nt < 8; nt++)
            #pragma unroll
            for (int r4 = 0; r4 < 4; r4++) {
                int row = mrow0 + q*4 + r4;
                int col = (nh*8 + nt)*16 + l15;
                sH[row*256 + ((col >> 3) ^ (row & 7))*8 + (col & 7)] = (bf16_t)siluf(acc[nt][r4]);
            }
        __syncthreads();
    }

    // ---- fused pooling: 2 row-halves x 256 cols, batch-run reduction ----
    {
        int j = t & 255;
        int rh = t >> 8;
        int g = j >> 3, jo = j & 7;
        int cur = -1;
        float run = 0.f;
        for (int i = rh*32; i < rh*32 + 32; i++) {
            int bb = s_batch[i];
            if (bb != cur) {
                if (cur >= 0) atomicAdd(&pooled[cur * MLP + j], run);
                run = 0.f; cur = bb;
            }
            if (bb >= 0) run += (float)sH[i*256 + (g ^ (i & 7))*8 + jo];
        }
        if (cur >= 0) atomicAdd(&pooled[cur * MLP + j], run);
    }
}

// ---------------- final: sigmoid((pooled/cnt) @ fow + fob) ------------------
__global__ void final_kernel(const float* __restrict__ pooled, const float* __restrict__ cnt,
                             const float* __restrict__ fow, const float* __restrict__ fob,
                             float* __restrict__ out)
{
    int t = threadIdx.x;
    int bg = t >> 2, o = t & 3;
    float c = fmaxf(cnt[bg], 1.0f);
    float acc = 0.f;
    for (int i = 0; i < MLP; i++) acc = fmaf(pooled[bg * MLP + i], fow[i * 4 + o], acc);
    acc = acc / c + fob[o];
    out[t] = 1.0f / (1.0f + __expf(-acc));
}

extern "C" void kernel_launch(void* const* d_in, const int* in_sizes, int n_in,
                              void* d_out, int out_size, void* d_ws, size_t ws_size,
                              hipStream_t stream)
{
    const int*   z     = (const int*)  d_in[0];
    const float* pos   = (const float*)d_in[1];
    const int*   eidx  = (const int*)  d_in[2];
    const int*   batch = (const int*)  d_in[3];
    const float* embt  = (const float*)d_in[4];
    const float* embw  = (const float*)d_in[5];
    const float* embb  = (const float*)d_in[6];
    const float* ew1   = (const float*)d_in[7];
    const float* eb1   = (const float*)d_in[8];
    const float* ew2   = (const float*)d_in[9];
    const float* eb2   = (const float*)d_in[10];
    const float* cw1   = (const float*)d_in[11];
    const float* cb1   = (const float*)d_in[12];
    const float* cw2   = (const float*)d_in[13];
    const float* cb2   = (const float*)d_in[14];
    const float* nw1   = (const float*)d_in[15];
    const float* nb1   = (const float*)d_in[16];
    const float* nw2   = (const float*)d_in[17];
    const float* nb2   = (const float*)d_in[18];
    const float* f0w   = (const float*)d_in[19];
    const float* f0b   = (const float*)d_in[20];
    const float* f1w   = (const float*)d_in[21];
    const float* f1b   = (const float*)d_in[22];
    const float* f2w   = (const float*)d_in[23];
    const float* f2b   = (const float*)d_in[24];
    const float* fow   = (const float*)d_in[25];
    const float* fob   = (const float*)d_in[26];

    float* ws     = (float*)d_ws;
    float* f0     = ws;
    float* f1v    = f0 + (size_t)N_NODES * EMB;
    float* f2v    = f1v + (size_t)N_NODES * EMB;
    bf16_t* fb0   = (bf16_t*)(f2v + (size_t)N_NODES * EMB);
    bf16_t* fb1   = fb0 + (size_t)N_NODES * EMB;
    float* coorsA = (float*)(fb1 + (size_t)N_NODES * EMB);
    float* cdelta = coorsA + N_NODES * 3;
    float* m_i    = cdelta + N_NODES * 3;
    float* pooled = m_i + (size_t)N_NODES * MDIM;
    float* cnt    = pooled + N_GRAPHS * MLP;
    int*   deg    = (int*)(cnt + N_GRAPHS);
    int*   cursor = deg + N_NODES;
    int*   srcs_s = cursor + N_NODES;
    int*   dsts_s = srcs_s + N_EDGES;
    bf16_t* packw = (bf16_t*)(dsts_s + N_EDGES);
    bf16_t* W1t0  = packw;
    bf16_t* W1t1  = W1t0 + PK_W1;
    bf16_t* W2t0  = W1t1 + PK_W1;
    bf16_t* W2t1  = W2t0 + PK_W2;
    bf16_t* CW1t  = W2t1 + PK_W2;
    bf16_t* W0p   = CW1t + PK_CW;
    bf16_t* W1p   = W0p + PK_F0;
    bf16_t* W2p   = W1p + PK_FM;

    hipMemsetAsync(cdelta, 0, N_NODES * 3 * sizeof(float), stream);
    hipMemsetAsync(m_i, 0, (size_t)N_NODES * MDIM * sizeof(float), stream);
    hipMemsetAsync(pooled, 0, (N_GRAPHS * MLP + N_GRAPHS) * sizeof(float), stream);
    hipMemsetAsync(deg, 0, N_NODES * sizeof(int), stream);

    const int* e_src = eidx;
    const int* e_dst = eidx + N_EDGES;
    pack_kernel<<<(PK_TOT + 255) / 256, 256, 0, stream>>>(ew1, eb1, ew2, eb2, cw1,
                                                          f0w, f1w, f2w, packw);
    hist_kernel<<<(N_EDGES + 255) / 256, 256, 0, stream>>>(e_dst, deg);
    scan_kernel<<<1, 1024, 0, stream>>>(deg, cursor);
    scatter_kernel<<<(N_EDGES + 255) / 256, 256, 0, stream>>>(e_src, e_dst, cursor, srcs_s, dsts_s);

    embed_kernel<<<(N_NODES + 255) / 256, 256, 0, stream>>>(z, embt, embw, embb, batch, f0, fb0, cnt);

    const int EBLK = N_EDGES / ETILE; // 6250
    edge_mfma<1><<<EBLK, 256, 0, stream>>>(fb0, pos, srcs_s, dsts_s,
        W1t0, W2t0, CW1t, cb1, cw2, cb2, m_i, cdelta);
    node_kernel<1><<<(N_NODES + 255) / 256, 256, 0, stream>>>(f0, m_i, nw1, nb1, nw2, nb2, f1v, fb1);
    coor_kernel<<<(N_NODES * 3 + 255) / 256, 256, 0, stream>>>(pos, cdelta, coorsA);
    hipMemsetAsync(m_i, 0, (size_t)N_NODES * MDIM * sizeof(float), stream);
    edge_mfma<0><<<EBLK, 256, 0, stream>>>(fb1, coorsA, srcs_s, dsts_s,
        W1t1, W2t1, CW1t, cb1, cw2, cb2, m_i, nullptr);
    node_kernel<0><<<(N_NODES + 255) / 256, 256, 0, stream>>>(f1v, m_i,
        nw1 + NIN * NH, nb1 + NH, nw2 + NH * EMB, nb2 + EMB, f2v, nullptr);

    const int FBLK = (N_NODES + NTILE - 1) / NTILE;
    ffnn_fused<<<FBLK, 512, 0, stream>>>(f0, f1v, f2v, W0p, W1p, W2p,
                                         f0b, f1b, f2b, batch, pooled);

    final_kernel<<<1, 256, 0, stream>>>(pooled, cnt, fow, fob, (float*)d_out);
}